// Round 6
// baseline (516.128 us; speedup 1.0000x reference)
//
#include <hip/hip_runtime.h>
#include <hip/hip_bf16.h>
#include <math.h>

#define BK_SHIFT 7            // 128 nodes per bucket
#define BK_NODES 128

typedef _Float16 h2 __attribute__((ext_vector_type(2)));

__device__ __forceinline__ h2 u2h(unsigned u){ return __builtin_bit_cast(h2, u); }

// ---------------- device helpers ----------------
__device__ __forceinline__ int dev_lower_bound(const int* __restrict__ a, int n, int v){
  int lo = 0, hi = n;
  while (lo < hi){ int mid = (lo + hi) >> 1; if (a[mid] < v) lo = mid + 1; else hi = mid; }
  return lo;
}

// ================= bucketed CSR build =================
__global__ __launch_bounds__(256) void p1_bucket_count(const int* __restrict__ edst,
    int* __restrict__ bktTotal, int nE, int K){
  __shared__ int cnt[512];
  for (int k = threadIdx.x; k < K; k += 256) cnt[k] = 0;
  __syncthreads();
  int i = (blockIdx.x * 256 + threadIdx.x) * 8;
  if (i + 7 < nE){
    int4 a = *(const int4*)(edst + i);
    int4 b = *(const int4*)(edst + i + 4);
    atomicAdd(&cnt[a.x >> BK_SHIFT], 1); atomicAdd(&cnt[a.y >> BK_SHIFT], 1);
    atomicAdd(&cnt[a.z >> BK_SHIFT], 1); atomicAdd(&cnt[a.w >> BK_SHIFT], 1);
    atomicAdd(&cnt[b.x >> BK_SHIFT], 1); atomicAdd(&cnt[b.y >> BK_SHIFT], 1);
    atomicAdd(&cnt[b.z >> BK_SHIFT], 1); atomicAdd(&cnt[b.w >> BK_SHIFT], 1);
  } else {
    for (int j = i; j < nE; ++j) atomicAdd(&cnt[edst[j] >> BK_SHIFT], 1);
  }
  __syncthreads();
  for (int k = threadIdx.x; k < K; k += 256)
    if (cnt[k]) atomicAdd(&bktTotal[k], cnt[k]);
}

__global__ __launch_bounds__(512) void p2_scan(const int* __restrict__ bktTotal,
    int* __restrict__ bktBase, int* __restrict__ bktCur,
    int* __restrict__ row_off, int K, int n, int nE){
  __shared__ int sh[512];
  int t = threadIdx.x;
  int v = (t < K) ? bktTotal[t] : 0;
  sh[t] = v;
  __syncthreads();
  for (int off = 1; off < 512; off <<= 1){
    int u = (t >= off) ? sh[t - off] : 0;
    __syncthreads();
    sh[t] += u;
    __syncthreads();
  }
  if (t < K){
    int excl = sh[t] - v;
    bktBase[t] = excl;
    bktCur[t]  = excl;
  }
  if (t == 0){
    bktBase[K] = nE;
    row_off[n] = nE + n;
  }
}

__global__ __launch_bounds__(256) void p3_partition(const int* __restrict__ esrc,
    const int* __restrict__ edst, int* __restrict__ bktCur,
    int2* __restrict__ ebuf, int nE, int K){
  __shared__ int cnt[512];
  __shared__ int base[512];
  for (int k = threadIdx.x; k < K; k += 256) cnt[k] = 0;
  __syncthreads();
  const int i0 = (blockIdx.x * 256 + threadIdx.x) * 8;
  const int i1 = min(i0 + 8, nE);
  int bkt[8];
  int sv[8], dv[8];
  int cnt_local = i1 - i0;
  for (int j = 0; j < cnt_local; ++j){
    sv[j] = esrc[i0 + j];
    dv[j] = edst[i0 + j];
    bkt[j] = dv[j] >> BK_SHIFT;
    atomicAdd(&cnt[bkt[j]], 1);
  }
  __syncthreads();
  for (int k = threadIdx.x; k < K; k += 256){
    int c = cnt[k];
    base[k] = c ? atomicAdd(&bktCur[k], c) : 0;
  }
  __syncthreads();
  for (int k = threadIdx.x; k < K; k += 256) cnt[k] = 0;
  __syncthreads();
  for (int j = 0; j < cnt_local; ++j){
    int r = atomicAdd(&cnt[bkt[j]], 1);
    ebuf[base[bkt[j]] + r] = make_int2(sv[j], dv[j]);
  }
}

__global__ __launch_bounds__(256) void p4_build(const int2* __restrict__ ebuf,
    const int* __restrict__ bktBase, int* __restrict__ row_off,
    int* __restrict__ csr_src, int n){
  const int b = blockIdx.x;
  const int node0 = b << BK_SHIFT;
  const int nNodes = min(BK_NODES, n - node0);
  const int tid = threadIdx.x;
  __shared__ int ldeg[BK_NODES];
  __shared__ int lcur[BK_NODES];
  __shared__ int sc[BK_NODES];
  const int e0 = bktBase[b];
  const int e1 = bktBase[b + 1];
  if (tid < BK_NODES) ldeg[tid] = 0;
  __syncthreads();
  for (int i = e0 + tid; i < e1; i += 256)
    atomicAdd(&ldeg[ebuf[i].y - node0], 1);
  __syncthreads();
  if (tid < BK_NODES) sc[tid] = (tid < nNodes) ? (ldeg[tid] + 1) : 0;
  __syncthreads();
  for (int off = 1; off < BK_NODES; off <<= 1){
    int u = 0;
    if (tid < BK_NODES && tid >= off) u = sc[tid - off];
    __syncthreads();
    if (tid < BK_NODES) sc[tid] += u;
    __syncthreads();
  }
  if (tid < nNodes){
    const int csr0 = e0 + node0;
    int ro = csr0 + sc[tid] - (ldeg[tid] + 1);
    row_off[node0 + tid] = ro;
    lcur[tid] = ro;
  }
  __syncthreads();
  for (int i = e0 + tid; i < e1; i += 256){
    int2 e = ebuf[i];
    int p = atomicAdd(&lcur[e.y - node0], 1);
    csr_src[p] = e.x;
  }
  __syncthreads();
  if (tid < nNodes)
    csr_src[lcur[tid]] = node0 + tid;
}

// ---------------- fused xl/xr GEMM: tile 128x128, K=128; output f16 ----------
__global__ __launch_bounds__(512) void gemm_xlxr_kernel(
    const float* __restrict__ X,
    const float* __restrict__ Wl, const float* __restrict__ bl,
    const float* __restrict__ Wr, const float* __restrict__ br,
    unsigned short* __restrict__ xl16, unsigned short* __restrict__ xr16, int n)
{
  const bool left = (blockIdx.y == 0);
  const float* W = left ? Wl : Wr;
  const float* b = left ? bl : br;
  unsigned short* o16 = left ? xl16 : xr16;
  __shared__ float Ws[32][128];
  __shared__ float Xs[128][36];
  const int tid = threadIdx.x;
  const int row0 = blockIdx.x * 128;
  const int tc = tid & 31;
  const int tr = tid >> 5;
  float acc[8][4] = {};
  for (int kc = 0; kc < 128; kc += 32){
    for (int idx = tid; idx < 1024; idx += 512){
      int r = idx >> 5, c4 = idx & 31;
      *(float4*)(&Ws[r][c4 * 4]) = *(const float4*)(W + (size_t)(kc + r) * 128 + c4 * 4);
    }
    for (int idx = tid; idx < 1024; idx += 512){
      int r = idx >> 3, c4 = idx & 7;
      int grow = row0 + r;
      float4 v = make_float4(0.f, 0.f, 0.f, 0.f);
      if (grow < n) v = *(const float4*)(X + (size_t)grow * 128 + kc + c4 * 4);
      *(float4*)(&Xs[r][c4 * 4]) = v;
    }
    __syncthreads();
    #pragma unroll
    for (int k = 0; k < 32; ++k){
      float4 w = *(const float4*)(&Ws[k][tc * 4]);
      #pragma unroll
      for (int r = 0; r < 8; ++r){
        float xv = Xs[tr * 8 + r][k];
        acc[r][0] = fmaf(xv, w.x, acc[r][0]);
        acc[r][1] = fmaf(xv, w.y, acc[r][1]);
        acc[r][2] = fmaf(xv, w.z, acc[r][2]);
        acc[r][3] = fmaf(xv, w.w, acc[r][3]);
      }
    }
    __syncthreads();
  }
  float4 bv = *(const float4*)(b + tc * 4);
  #pragma unroll
  for (int r = 0; r < 8; ++r){
    int grow = row0 + tr * 8 + r;
    if (grow < n){
      _Float16 h0 = (_Float16)(acc[r][0] + bv.x);
      _Float16 h1 = (_Float16)(acc[r][1] + bv.y);
      _Float16 h2v= (_Float16)(acc[r][2] + bv.z);
      _Float16 h3 = (_Float16)(acc[r][3] + bv.w);
      ushort4 o;
      o.x = __builtin_bit_cast(unsigned short, h0);
      o.y = __builtin_bit_cast(unsigned short, h1);
      o.z = __builtin_bit_cast(unsigned short, h2v);
      o.w = __builtin_bit_cast(unsigned short, h3);
      *(ushort4*)(o16 + (size_t)grow * 128 + tc * 4) = o;
    }
  }
}

// ---------------- per-destination online-softmax attention ----------------
// One 16-lane quarter-wave per destination node; 8 f16 features per lane.
// Packed-f16 score (pk_add/pk_mul/pk_max + v_dot2_f32_f16), 4-step shfl
// reduce, defer-max online softmax (peel edge 0; rescale only on overflow risk).
__global__ __launch_bounds__(256) void edge_attn_kernel(
    const unsigned short* __restrict__ xl16, const unsigned short* __restrict__ xr16,
    const int* __restrict__ row_off, const int* __restrict__ csr_src,
    const float* __restrict__ att, const float* __restrict__ bias,
    float* __restrict__ out, int n, int do_relu)
{
  const int node = (blockIdx.x * blockDim.x + threadIdx.x) >> 4;
  const int nodec = min(node, n - 1);
  const int lane16 = threadIdx.x & 15;
  const int f8 = lane16 * 8;

  const uint4 xru = *(const uint4*)(xr16 + (size_t)nodec * 128 + f8);
  const h2 xr0 = u2h(xru.x), xr1 = u2h(xru.y), xr2 = u2h(xru.z), xr3 = u2h(xru.w);
  const float4 aA = *(const float4*)(att + f8);
  const float4 aB = *(const float4*)(att + f8 + 4);
  const h2 at0 = {(_Float16)aA.x, (_Float16)aA.y};
  const h2 at1 = {(_Float16)aA.z, (_Float16)aA.w};
  const h2 at2 = {(_Float16)aB.x, (_Float16)aB.y};
  const h2 at3 = {(_Float16)aB.z, (_Float16)aB.w};
  const h2 k02 = {(_Float16)0.2f, (_Float16)0.2f};

  const int base = row_off[nodec];
  const int deg  = row_off[nodec + 1] - base;      // >= 1 (self-loop)
  int dmax = max(deg, __shfl_xor(deg, 16));
  dmax = max(dmax, __shfl_xor(dmax, 32));          // wave-uniform bound

  auto score = [&](uint4 xp) -> float {
    h2 u0 = u2h(xp.x) + xr0;
    h2 u1 = u2h(xp.y) + xr1;
    h2 u2 = u2h(xp.z) + xr2;
    h2 u3 = u2h(xp.w) + xr3;
    u0 = __builtin_elementwise_max(u0, u0 * k02);  // leaky_relu .2
    u1 = __builtin_elementwise_max(u1, u1 * k02);
    u2 = __builtin_elementwise_max(u2, u2 * k02);
    u3 = __builtin_elementwise_max(u3, u3 * k02);
    float ps = __builtin_amdgcn_fdot2(u0, at0, 0.f, false);
    ps = __builtin_amdgcn_fdot2(u1, at1, ps, false);
    ps = __builtin_amdgcn_fdot2(u2, at2, ps, false);
    ps = __builtin_amdgcn_fdot2(u3, at3, ps, false);
    ps += __shfl_xor(ps, 1);
    ps += __shfl_xor(ps, 2);
    ps += __shfl_xor(ps, 4);
    ps += __shfl_xor(ps, 8);                       // uniform across quarter
    return ps;
  };

  // peel edge 0 (always exists): m = p0, s = 1, acc = x0
  uint4 xp = *(const uint4*)(xl16 + (size_t)csr_src[base] * 128 + f8);
  float m = score(xp);
  float Mrun = m, s = 1.f;
  h2 v0 = u2h(xp.x), v1 = u2h(xp.y), v2 = u2h(xp.z), v3 = u2h(xp.w);
  float a0 = (float)v0.x, a1 = (float)v0.y, a2 = (float)v1.x, a3 = (float)v1.y;
  float a4 = (float)v2.x, a5 = (float)v2.y, a6 = (float)v3.x, a7 = (float)v3.y;

  for (int it = 1; it < dmax; ++it){
    const int c = min(it, deg - 1);
    const int sidx = csr_src[base + c];
    const uint4 xq = *(const uint4*)(xl16 + (size_t)sidx * 128 + f8);
    const float p = score(xq);
    const bool valid = it < deg;
    Mrun = fmaxf(Mrun, valid ? p : -3.0e38f);
    if (__any(Mrun > m + 8.f)){                    // rare, wave-uniform
      float sc = __expf(m - Mrun);                 // ==1 for unaffected quarters
      s *= sc;
      a0 *= sc; a1 *= sc; a2 *= sc; a3 *= sc;
      a4 *= sc; a5 *= sc; a6 *= sc; a7 *= sc;
      m = Mrun;
    }
    float q = __expf(p - m);
    q = valid ? q : 0.f;
    s += q;
    v0 = u2h(xq.x); v1 = u2h(xq.y); v2 = u2h(xq.z); v3 = u2h(xq.w);
    a0 = fmaf(q, (float)v0.x, a0); a1 = fmaf(q, (float)v0.y, a1);
    a2 = fmaf(q, (float)v1.x, a2); a3 = fmaf(q, (float)v1.y, a3);
    a4 = fmaf(q, (float)v2.x, a4); a5 = fmaf(q, (float)v2.y, a5);
    a6 = fmaf(q, (float)v3.x, a6); a7 = fmaf(q, (float)v3.y, a7);
  }

  if (node < n){
    const float inv = 1.0f / s;                    // s >= exp(-8) by construction
    const float4 bA = *(const float4*)(bias + f8);
    const float4 bB = *(const float4*)(bias + f8 + 4);
    float o0 = fmaf(a0, inv, bA.x), o1 = fmaf(a1, inv, bA.y);
    float o2 = fmaf(a2, inv, bA.z), o3 = fmaf(a3, inv, bA.w);
    float o4 = fmaf(a4, inv, bB.x), o5 = fmaf(a5, inv, bB.y);
    float o6 = fmaf(a6, inv, bB.z), o7 = fmaf(a7, inv, bB.w);
    if (do_relu){
      o0 = fmaxf(o0, 0.f); o1 = fmaxf(o1, 0.f); o2 = fmaxf(o2, 0.f); o3 = fmaxf(o3, 0.f);
      o4 = fmaxf(o4, 0.f); o5 = fmaxf(o5, 0.f); o6 = fmaxf(o6, 0.f); o7 = fmaxf(o7, 0.f);
    }
    *(float4*)(out + (size_t)node * 128 + f8)     = make_float4(o0, o1, o2, o3);
    *(float4*)(out + (size_t)node * 128 + f8 + 4) = make_float4(o4, o5, o6, o7);
  }
}

// ---------------- mean-pool + MLP head ----------------
__global__ __launch_bounds__(128) void pool_mlp_kernel(
    const float* __restrict__ h, const int* __restrict__ batch, int n,
    const float* __restrict__ W4, const float* __restrict__ b4,
    const float* __restrict__ W5, const float* __restrict__ b5,
    const float* __restrict__ W6, const float* __restrict__ b6,
    float* __restrict__ out)
{
  int g = blockIdx.x;
  int t = threadIdx.x;
  __shared__ float gf[128];
  __shared__ float h1[128];
  __shared__ float h2s[64];
  int lo = dev_lower_bound(batch, n, g);
  int hi = dev_lower_bound(batch, n, g + 1);
  float ssum = 0.f;
  for (int i = lo; i < hi; ++i) ssum += h[(size_t)i * 128 + t];
  float cnt = (float)(hi - lo);
  gf[t] = ssum / fmaxf(cnt, 1.0f);
  __syncthreads();
  float a = b4[t];
  for (int k = 0; k < 128; ++k) a = fmaf(gf[k], W4[k * 128 + t], a);
  h1[t] = 1.0f / (1.0f + __expf(-a));
  __syncthreads();
  if (t < 64){
    float a5 = b5[t];
    for (int k = 0; k < 128; ++k) a5 = fmaf(h1[k], W5[k * 64 + t], a5);
    h2s[t] = 1.0f / (1.0f + __expf(-a5));
  }
  __syncthreads();
  if (t < 2){
    float a6 = b6[t];
    for (int k = 0; k < 64; ++k) a6 = fmaf(h2s[k], W6[k * 2 + t], a6);
    out[g * 2 + t] = a6;
  }
}

// ---------------- launcher ----------------
extern "C" void kernel_launch(void* const* d_in, const int* in_sizes, int n_in,
                              void* d_out, int out_size, void* d_ws, size_t ws_size,
                              hipStream_t stream)
{
  const float* x          = (const float*)d_in[0];
  const int*   edge_index = (const int*)d_in[1];
  const int*   batch      = (const int*)d_in[2];
  const int n  = in_sizes[0] / 128;            // 50000
  const int nE = in_sizes[1] / 2;              // 1600000
  const int* esrc = edge_index;
  const int* edst = edge_index + nE;
  const int n_graphs = out_size / 2;           // 512
  const int K = (n + BK_NODES - 1) >> BK_SHIFT;

  const float *Wl[3], *bl[3], *Wr[3], *br[3], *att[3], *bias[3];
  for (int l = 0; l < 3; ++l){
    Wl[l]   = (const float*)d_in[3 + 6 * l + 0];
    bl[l]   = (const float*)d_in[3 + 6 * l + 1];
    Wr[l]   = (const float*)d_in[3 + 6 * l + 2];
    br[l]   = (const float*)d_in[3 + 6 * l + 3];
    att[l]  = (const float*)d_in[3 + 6 * l + 4];
    bias[l] = (const float*)d_in[3 + 6 * l + 5];
  }
  const float* W4 = (const float*)d_in[21]; const float* b4 = (const float*)d_in[22];
  const float* W5 = (const float*)d_in[23]; const float* b5 = (const float*)d_in[24];
  const float* W6 = (const float*)d_in[25]; const float* b6 = (const float*)d_in[26];

  char* ws = (char*)d_ws;
  size_t off = 0;
  auto alloc = [&](size_t bytes) -> void* {
    void* p = ws + off;
    off = (off + bytes + 255) & ~(size_t)255;
    return p;
  };
  int*   row_off  = (int*)  alloc((size_t)(n + 1) * sizeof(int));
  int*   bktTotal = (int*)  alloc(512 * sizeof(int));
  int*   bktBase  = (int*)  alloc(513 * sizeof(int));
  int*   bktCur   = (int*)  alloc(512 * sizeof(int));
  int*   csr_src  = (int*)  alloc((size_t)(nE + n) * sizeof(int));
  int2*  ebuf     = (int2*) alloc((size_t)nE * sizeof(int2));
  unsigned short* xlb16 = (unsigned short*)alloc((size_t)n * 128 * sizeof(unsigned short));
  unsigned short* xrb16 = (unsigned short*)alloc((size_t)n * 128 * sizeof(unsigned short));
  float* hC       = (float*)alloc((size_t)n * 128 * sizeof(float));
  (void)ws_size; (void)n_in;

  // ---- bucketed CSR build ----
  hipMemsetAsync(bktTotal, 0, 512 * sizeof(int), stream);
  const int eblocks = (nE + 2048 - 1) / 2048;
  p1_bucket_count<<<eblocks, 256, 0, stream>>>(edst, bktTotal, nE, K);
  p2_scan<<<1, 512, 0, stream>>>(bktTotal, bktBase, bktCur, row_off, K, n, nE);
  p3_partition<<<eblocks, 256, 0, stream>>>(esrc, edst, bktCur, ebuf, nE, K);
  p4_build<<<K, 256, 0, stream>>>(ebuf, bktBase, row_off, csr_src, n);

  const int gemm_tiles = (n + 127) / 128;
  const int attn_blocks = (int)(((size_t)n * 16 + 255) / 256);

  // layer 1
  gemm_xlxr_kernel<<<dim3(gemm_tiles, 2), 512, 0, stream>>>(x, Wl[0], bl[0], Wr[0], br[0],
                                                            xlb16, xrb16, n);
  edge_attn_kernel<<<attn_blocks, 256, 0, stream>>>(xlb16, xrb16, row_off, csr_src,
                                                    att[0], bias[0], hC, n, 1);
  // layer 2
  gemm_xlxr_kernel<<<dim3(gemm_tiles, 2), 512, 0, stream>>>(hC, Wl[1], bl[1], Wr[1], br[1],
                                                            xlb16, xrb16, n);
  edge_attn_kernel<<<attn_blocks, 256, 0, stream>>>(xlb16, xrb16, row_off, csr_src,
                                                    att[1], bias[1], hC, n, 1);
  // layer 3
  gemm_xlxr_kernel<<<dim3(gemm_tiles, 2), 512, 0, stream>>>(hC, Wl[2], bl[2], Wr[2], br[2],
                                                            xlb16, xrb16, n);
  edge_attn_kernel<<<attn_blocks, 256, 0, stream>>>(xlb16, xrb16, row_off, csr_src,
                                                    att[2], bias[2], hC, n, 0);

  pool_mlp_kernel<<<n_graphs, 128, 0, stream>>>(hC, batch, n, W4, b4, W5, b5, W6, b6,
                                                (float*)d_out);
}

// Round 7
// 458.375 us; speedup vs baseline: 1.1260x; 1.1260x over previous
//
#include <hip/hip_runtime.h>
#include <hip/hip_bf16.h>
#include <math.h>

#define BK_SHIFT 7            // 128 nodes per bucket
#define BK_NODES 128

typedef _Float16 h2 __attribute__((ext_vector_type(2)));

__device__ __forceinline__ h2 u2h(unsigned u){ return __builtin_bit_cast(h2, u); }

// ---------------- device helpers ----------------
__device__ __forceinline__ int dev_lower_bound(const int* __restrict__ a, int n, int v){
  int lo = 0, hi = n;
  while (lo < hi){ int mid = (lo + hi) >> 1; if (a[mid] < v) lo = mid + 1; else hi = mid; }
  return lo;
}

// ================= bucketed CSR build =================
__global__ __launch_bounds__(256) void p1_bucket_count(const int* __restrict__ edst,
    int* __restrict__ bktTotal, int nE, int K){
  __shared__ int cnt[512];
  for (int k = threadIdx.x; k < K; k += 256) cnt[k] = 0;
  __syncthreads();
  int i = (blockIdx.x * 256 + threadIdx.x) * 8;
  if (i + 7 < nE){
    int4 a = *(const int4*)(edst + i);
    int4 b = *(const int4*)(edst + i + 4);
    atomicAdd(&cnt[a.x >> BK_SHIFT], 1); atomicAdd(&cnt[a.y >> BK_SHIFT], 1);
    atomicAdd(&cnt[a.z >> BK_SHIFT], 1); atomicAdd(&cnt[a.w >> BK_SHIFT], 1);
    atomicAdd(&cnt[b.x >> BK_SHIFT], 1); atomicAdd(&cnt[b.y >> BK_SHIFT], 1);
    atomicAdd(&cnt[b.z >> BK_SHIFT], 1); atomicAdd(&cnt[b.w >> BK_SHIFT], 1);
  } else {
    for (int j = i; j < nE; ++j) atomicAdd(&cnt[edst[j] >> BK_SHIFT], 1);
  }
  __syncthreads();
  for (int k = threadIdx.x; k < K; k += 256)
    if (cnt[k]) atomicAdd(&bktTotal[k], cnt[k]);
}

__global__ __launch_bounds__(512) void p2_scan(const int* __restrict__ bktTotal,
    int* __restrict__ bktBase, int* __restrict__ bktCur,
    int* __restrict__ row_off, int K, int n, int nE){
  __shared__ int sh[512];
  int t = threadIdx.x;
  int v = (t < K) ? bktTotal[t] : 0;
  sh[t] = v;
  __syncthreads();
  for (int off = 1; off < 512; off <<= 1){
    int u = (t >= off) ? sh[t - off] : 0;
    __syncthreads();
    sh[t] += u;
    __syncthreads();
  }
  if (t < K){
    int excl = sh[t] - v;
    bktBase[t] = excl;
    bktCur[t]  = excl;
  }
  if (t == 0){
    bktBase[K] = nE;
    row_off[n] = nE + n;
  }
}

__global__ __launch_bounds__(256) void p3_partition(const int* __restrict__ esrc,
    const int* __restrict__ edst, int* __restrict__ bktCur,
    int2* __restrict__ ebuf, int nE, int K){
  __shared__ int cnt[512];
  __shared__ int base[512];
  for (int k = threadIdx.x; k < K; k += 256) cnt[k] = 0;
  __syncthreads();
  const int i0 = (blockIdx.x * 256 + threadIdx.x) * 8;
  const int i1 = min(i0 + 8, nE);
  int bkt[8];
  int sv[8], dv[8];
  int cnt_local = i1 - i0;
  for (int j = 0; j < cnt_local; ++j){
    sv[j] = esrc[i0 + j];
    dv[j] = edst[i0 + j];
    bkt[j] = dv[j] >> BK_SHIFT;
    atomicAdd(&cnt[bkt[j]], 1);
  }
  __syncthreads();
  for (int k = threadIdx.x; k < K; k += 256){
    int c = cnt[k];
    base[k] = c ? atomicAdd(&bktCur[k], c) : 0;
  }
  __syncthreads();
  for (int k = threadIdx.x; k < K; k += 256) cnt[k] = 0;
  __syncthreads();
  for (int j = 0; j < cnt_local; ++j){
    int r = atomicAdd(&cnt[bkt[j]], 1);
    ebuf[base[bkt[j]] + r] = make_int2(sv[j], dv[j]);
  }
}

__global__ __launch_bounds__(256) void p4_build(const int2* __restrict__ ebuf,
    const int* __restrict__ bktBase, int* __restrict__ row_off,
    int* __restrict__ csr_src, int n){
  const int b = blockIdx.x;
  const int node0 = b << BK_SHIFT;
  const int nNodes = min(BK_NODES, n - node0);
  const int tid = threadIdx.x;
  __shared__ int ldeg[BK_NODES];
  __shared__ int lcur[BK_NODES];
  __shared__ int sc[BK_NODES];
  const int e0 = bktBase[b];
  const int e1 = bktBase[b + 1];
  if (tid < BK_NODES) ldeg[tid] = 0;
  __syncthreads();
  for (int i = e0 + tid; i < e1; i += 256)
    atomicAdd(&ldeg[ebuf[i].y - node0], 1);
  __syncthreads();
  if (tid < BK_NODES) sc[tid] = (tid < nNodes) ? (ldeg[tid] + 1) : 0;
  __syncthreads();
  for (int off = 1; off < BK_NODES; off <<= 1){
    int u = 0;
    if (tid < BK_NODES && tid >= off) u = sc[tid - off];
    __syncthreads();
    if (tid < BK_NODES) sc[tid] += u;
    __syncthreads();
  }
  if (tid < nNodes){
    const int csr0 = e0 + node0;
    int ro = csr0 + sc[tid] - (ldeg[tid] + 1);
    row_off[node0 + tid] = ro;
    lcur[tid] = ro;
  }
  __syncthreads();
  for (int i = e0 + tid; i < e1; i += 256){
    int2 e = ebuf[i];
    int p = atomicAdd(&lcur[e.y - node0], 1);
    csr_src[p] = e.x;
  }
  __syncthreads();
  if (tid < nNodes)
    csr_src[lcur[tid]] = node0 + tid;
}

// ---------------- fused xl/xr GEMM: tile 128x128, K=128; output f16 ----------
__global__ __launch_bounds__(512) void gemm_xlxr_kernel(
    const float* __restrict__ X,
    const float* __restrict__ Wl, const float* __restrict__ bl,
    const float* __restrict__ Wr, const float* __restrict__ br,
    unsigned short* __restrict__ xl16, unsigned short* __restrict__ xr16, int n)
{
  const bool left = (blockIdx.y == 0);
  const float* W = left ? Wl : Wr;
  const float* b = left ? bl : br;
  unsigned short* o16 = left ? xl16 : xr16;
  __shared__ float Ws[32][128];
  __shared__ float Xs[128][36];
  const int tid = threadIdx.x;
  const int row0 = blockIdx.x * 128;
  const int tc = tid & 31;
  const int tr = tid >> 5;
  float acc[8][4] = {};
  for (int kc = 0; kc < 128; kc += 32){
    for (int idx = tid; idx < 1024; idx += 512){
      int r = idx >> 5, c4 = idx & 31;
      *(float4*)(&Ws[r][c4 * 4]) = *(const float4*)(W + (size_t)(kc + r) * 128 + c4 * 4);
    }
    for (int idx = tid; idx < 1024; idx += 512){
      int r = idx >> 3, c4 = idx & 7;
      int grow = row0 + r;
      float4 v = make_float4(0.f, 0.f, 0.f, 0.f);
      if (grow < n) v = *(const float4*)(X + (size_t)grow * 128 + kc + c4 * 4);
      *(float4*)(&Xs[r][c4 * 4]) = v;
    }
    __syncthreads();
    #pragma unroll
    for (int k = 0; k < 32; ++k){
      float4 w = *(const float4*)(&Ws[k][tc * 4]);
      #pragma unroll
      for (int r = 0; r < 8; ++r){
        float xv = Xs[tr * 8 + r][k];
        acc[r][0] = fmaf(xv, w.x, acc[r][0]);
        acc[r][1] = fmaf(xv, w.y, acc[r][1]);
        acc[r][2] = fmaf(xv, w.z, acc[r][2]);
        acc[r][3] = fmaf(xv, w.w, acc[r][3]);
      }
    }
    __syncthreads();
  }
  float4 bv = *(const float4*)(b + tc * 4);
  #pragma unroll
  for (int r = 0; r < 8; ++r){
    int grow = row0 + tr * 8 + r;
    if (grow < n){
      _Float16 h0 = (_Float16)(acc[r][0] + bv.x);
      _Float16 h1 = (_Float16)(acc[r][1] + bv.y);
      _Float16 h2v= (_Float16)(acc[r][2] + bv.z);
      _Float16 h3 = (_Float16)(acc[r][3] + bv.w);
      ushort4 o;
      o.x = __builtin_bit_cast(unsigned short, h0);
      o.y = __builtin_bit_cast(unsigned short, h1);
      o.z = __builtin_bit_cast(unsigned short, h2v);
      o.w = __builtin_bit_cast(unsigned short, h3);
      *(ushort4*)(o16 + (size_t)grow * 128 + tc * 4) = o;
    }
  }
}

// ---------------- per-destination online-softmax attention ----------------
// One 16-lane quarter per node, 8 f16 feats/lane, 4-edge unrolled pipeline:
// 4 independent row gathers in flight per wave-iteration (MLP x4), packed-f16
// score, defer-max online softmax.
__global__ __launch_bounds__(256) void edge_attn_kernel(
    const unsigned short* __restrict__ xl16, const unsigned short* __restrict__ xr16,
    const int* __restrict__ row_off, const int* __restrict__ csr_src,
    const float* __restrict__ att, const float* __restrict__ bias,
    float* __restrict__ out, int n, int do_relu)
{
  const int node = (blockIdx.x * blockDim.x + threadIdx.x) >> 4;
  const int nodec = min(node, n - 1);
  const int lane16 = threadIdx.x & 15;
  const int f8 = lane16 * 8;

  const uint4 xru = *(const uint4*)(xr16 + (size_t)nodec * 128 + f8);
  const h2 xr0 = u2h(xru.x), xr1 = u2h(xru.y), xr2 = u2h(xru.z), xr3 = u2h(xru.w);
  const float4 aA = *(const float4*)(att + f8);
  const float4 aB = *(const float4*)(att + f8 + 4);
  const h2 at0 = {(_Float16)aA.x, (_Float16)aA.y};
  const h2 at1 = {(_Float16)aA.z, (_Float16)aA.w};
  const h2 at2 = {(_Float16)aB.x, (_Float16)aB.y};
  const h2 at3 = {(_Float16)aB.z, (_Float16)aB.w};
  const h2 k02 = {(_Float16)0.2f, (_Float16)0.2f};

  const int base = row_off[nodec];
  const int deg  = row_off[nodec + 1] - base;      // >= 1 (self-loop)
  int dmax = max(deg, __shfl_xor(deg, 16));
  dmax = max(dmax, __shfl_xor(dmax, 32));          // wave-uniform bound

  // per-lane dot partial (no reduction)
  auto part = [&](uint4 xp) -> float {
    h2 u0 = u2h(xp.x) + xr0;
    h2 u1 = u2h(xp.y) + xr1;
    h2 u2 = u2h(xp.z) + xr2;
    h2 u3 = u2h(xp.w) + xr3;
    u0 = __builtin_elementwise_max(u0, u0 * k02);  // leaky_relu .2
    u1 = __builtin_elementwise_max(u1, u1 * k02);
    u2 = __builtin_elementwise_max(u2, u2 * k02);
    u3 = __builtin_elementwise_max(u3, u3 * k02);
    float ps = __builtin_amdgcn_fdot2(u0, at0, 0.f, false);
    ps = __builtin_amdgcn_fdot2(u1, at1, ps, false);
    ps = __builtin_amdgcn_fdot2(u2, at2, ps, false);
    ps = __builtin_amdgcn_fdot2(u3, at3, ps, false);
    return ps;
  };

  // peel edge 0 (always exists): m = p0, s = 1, acc = x0
  uint4 xp = *(const uint4*)(xl16 + (size_t)csr_src[base] * 128 + f8);
  float p = part(xp);
  p += __shfl_xor(p, 1); p += __shfl_xor(p, 2);
  p += __shfl_xor(p, 4); p += __shfl_xor(p, 8);
  float m = p, Mrun = p, s = 1.f;
  {
    h2 v0 = u2h(xp.x), v1 = u2h(xp.y), v2 = u2h(xp.z), v3 = u2h(xp.w);
    (void)v0;
  }
  float a0 = (float)u2h(xp.x).x, a1 = (float)u2h(xp.x).y;
  float a2 = (float)u2h(xp.y).x, a3 = (float)u2h(xp.y).y;
  float a4 = (float)u2h(xp.z).x, a5 = (float)u2h(xp.z).y;
  float a6 = (float)u2h(xp.w).x, a7 = (float)u2h(xp.w).y;

  for (int it = 1; it < dmax; it += 4){
    // ---- issue 4 independent gathers (MLP) ----
    const int c0 = min(it,     deg - 1);
    const int c1 = min(it + 1, deg - 1);
    const int c2 = min(it + 2, deg - 1);
    const int c3 = min(it + 3, deg - 1);
    const int s0 = csr_src[base + c0];
    const int s1 = csr_src[base + c1];
    const int s2 = csr_src[base + c2];
    const int s3 = csr_src[base + c3];
    const uint4 xA = *(const uint4*)(xl16 + (size_t)s0 * 128 + f8);
    const uint4 xB = *(const uint4*)(xl16 + (size_t)s1 * 128 + f8);
    const uint4 xC = *(const uint4*)(xl16 + (size_t)s2 * 128 + f8);
    const uint4 xD = *(const uint4*)(xl16 + (size_t)s3 * 128 + f8);
    // ---- 4 scores ----
    float pA = part(xA), pB = part(xB), pC = part(xC), pD = part(xD);
    #pragma unroll
    for (int off = 1; off < 16; off <<= 1){
      pA += __shfl_xor(pA, off);
      pB += __shfl_xor(pB, off);
      pC += __shfl_xor(pC, off);
      pD += __shfl_xor(pD, off);
    }
    const bool vA = it < deg, vB = it + 1 < deg, vC = it + 2 < deg, vD = it + 3 < deg;
    float fA = vA ? pA : -3.0e38f;
    float fB = vB ? pB : -3.0e38f;
    float fC = vC ? pC : -3.0e38f;
    float fD = vD ? pD : -3.0e38f;
    Mrun = fmaxf(Mrun, fmaxf(fmaxf(fA, fB), fmaxf(fC, fD)));
    if (__any(Mrun > m + 8.f)){                    // rare, wave-uniform
      float sc = __expf(m - Mrun);
      s *= sc;
      a0 *= sc; a1 *= sc; a2 *= sc; a3 *= sc;
      a4 *= sc; a5 *= sc; a6 *= sc; a7 *= sc;
      m = Mrun;
    }
    float qA = vA ? __expf(pA - m) : 0.f;
    float qB = vB ? __expf(pB - m) : 0.f;
    float qC = vC ? __expf(pC - m) : 0.f;
    float qD = vD ? __expf(pD - m) : 0.f;
    s += (qA + qB) + (qC + qD);
    h2 w;
    w = u2h(xA.x); a0 = fmaf(qA, (float)w.x, a0); a1 = fmaf(qA, (float)w.y, a1);
    w = u2h(xA.y); a2 = fmaf(qA, (float)w.x, a2); a3 = fmaf(qA, (float)w.y, a3);
    w = u2h(xA.z); a4 = fmaf(qA, (float)w.x, a4); a5 = fmaf(qA, (float)w.y, a5);
    w = u2h(xA.w); a6 = fmaf(qA, (float)w.x, a6); a7 = fmaf(qA, (float)w.y, a7);
    w = u2h(xB.x); a0 = fmaf(qB, (float)w.x, a0); a1 = fmaf(qB, (float)w.y, a1);
    w = u2h(xB.y); a2 = fmaf(qB, (float)w.x, a2); a3 = fmaf(qB, (float)w.y, a3);
    w = u2h(xB.z); a4 = fmaf(qB, (float)w.x, a4); a5 = fmaf(qB, (float)w.y, a5);
    w = u2h(xB.w); a6 = fmaf(qB, (float)w.x, a6); a7 = fmaf(qB, (float)w.y, a7);
    w = u2h(xC.x); a0 = fmaf(qC, (float)w.x, a0); a1 = fmaf(qC, (float)w.y, a1);
    w = u2h(xC.y); a2 = fmaf(qC, (float)w.x, a2); a3 = fmaf(qC, (float)w.y, a3);
    w = u2h(xC.z); a4 = fmaf(qC, (float)w.x, a4); a5 = fmaf(qC, (float)w.y, a5);
    w = u2h(xC.w); a6 = fmaf(qC, (float)w.x, a6); a7 = fmaf(qC, (float)w.y, a7);
    w = u2h(xD.x); a0 = fmaf(qD, (float)w.x, a0); a1 = fmaf(qD, (float)w.y, a1);
    w = u2h(xD.y); a2 = fmaf(qD, (float)w.x, a2); a3 = fmaf(qD, (float)w.y, a3);
    w = u2h(xD.z); a4 = fmaf(qD, (float)w.x, a4); a5 = fmaf(qD, (float)w.y, a5);
    w = u2h(xD.w); a6 = fmaf(qD, (float)w.x, a6); a7 = fmaf(qD, (float)w.y, a7);
  }

  if (node < n){
    const float inv = 1.0f / s;                    // s >= exp(-8) by construction
    const float4 bA = *(const float4*)(bias + f8);
    const float4 bB = *(const float4*)(bias + f8 + 4);
    float o0 = fmaf(a0, inv, bA.x), o1 = fmaf(a1, inv, bA.y);
    float o2 = fmaf(a2, inv, bA.z), o3 = fmaf(a3, inv, bA.w);
    float o4 = fmaf(a4, inv, bB.x), o5 = fmaf(a5, inv, bB.y);
    float o6 = fmaf(a6, inv, bB.z), o7 = fmaf(a7, inv, bB.w);
    if (do_relu){
      o0 = fmaxf(o0, 0.f); o1 = fmaxf(o1, 0.f); o2 = fmaxf(o2, 0.f); o3 = fmaxf(o3, 0.f);
      o4 = fmaxf(o4, 0.f); o5 = fmaxf(o5, 0.f); o6 = fmaxf(o6, 0.f); o7 = fmaxf(o7, 0.f);
    }
    *(float4*)(out + (size_t)node * 128 + f8)     = make_float4(o0, o1, o2, o3);
    *(float4*)(out + (size_t)node * 128 + f8 + 4) = make_float4(o4, o5, o6, o7);
  }
}

// ---------------- mean-pool + MLP head ----------------
__global__ __launch_bounds__(128) void pool_mlp_kernel(
    const float* __restrict__ h, const int* __restrict__ batch, int n,
    const float* __restrict__ W4, const float* __restrict__ b4,
    const float* __restrict__ W5, const float* __restrict__ b5,
    const float* __restrict__ W6, const float* __restrict__ b6,
    float* __restrict__ out)
{
  int g = blockIdx.x;
  int t = threadIdx.x;
  __shared__ float gf[128];
  __shared__ float h1[128];
  __shared__ float h2s[64];
  int lo = dev_lower_bound(batch, n, g);
  int hi = dev_lower_bound(batch, n, g + 1);
  float ssum = 0.f;
  for (int i = lo; i < hi; ++i) ssum += h[(size_t)i * 128 + t];
  float cnt = (float)(hi - lo);
  gf[t] = ssum / fmaxf(cnt, 1.0f);
  __syncthreads();
  float a = b4[t];
  for (int k = 0; k < 128; ++k) a = fmaf(gf[k], W4[k * 128 + t], a);
  h1[t] = 1.0f / (1.0f + __expf(-a));
  __syncthreads();
  if (t < 64){
    float a5 = b5[t];
    for (int k = 0; k < 128; ++k) a5 = fmaf(h1[k], W5[k * 64 + t], a5);
    h2s[t] = 1.0f / (1.0f + __expf(-a5));
  }
  __syncthreads();
  if (t < 2){
    float a6 = b6[t];
    for (int k = 0; k < 64; ++k) a6 = fmaf(h2s[k], W6[k * 2 + t], a6);
    out[g * 2 + t] = a6;
  }
}

// ---------------- launcher ----------------
extern "C" void kernel_launch(void* const* d_in, const int* in_sizes, int n_in,
                              void* d_out, int out_size, void* d_ws, size_t ws_size,
                              hipStream_t stream)
{
  const float* x          = (const float*)d_in[0];
  const int*   edge_index = (const int*)d_in[1];
  const int*   batch      = (const int*)d_in[2];
  const int n  = in_sizes[0] / 128;            // 50000
  const int nE = in_sizes[1] / 2;              // 1600000
  const int* esrc = edge_index;
  const int* edst = edge_index + nE;
  const int n_graphs = out_size / 2;           // 512
  const int K = (n + BK_NODES - 1) >> BK_SHIFT;

  const float *Wl[3], *bl[3], *Wr[3], *br[3], *att[3], *bias[3];
  for (int l = 0; l < 3; ++l){
    Wl[l]   = (const float*)d_in[3 + 6 * l + 0];
    bl[l]   = (const float*)d_in[3 + 6 * l + 1];
    Wr[l]   = (const float*)d_in[3 + 6 * l + 2];
    br[l]   = (const float*)d_in[3 + 6 * l + 3];
    att[l]  = (const float*)d_in[3 + 6 * l + 4];
    bias[l] = (const float*)d_in[3 + 6 * l + 5];
  }
  const float* W4 = (const float*)d_in[21]; const float* b4 = (const float*)d_in[22];
  const float* W5 = (const float*)d_in[23]; const float* b5 = (const float*)d_in[24];
  const float* W6 = (const float*)d_in[25]; const float* b6 = (const float*)d_in[26];

  char* ws = (char*)d_ws;
  size_t off = 0;
  auto alloc = [&](size_t bytes) -> void* {
    void* p = ws + off;
    off = (off + bytes + 255) & ~(size_t)255;
    return p;
  };
  int*   row_off  = (int*)  alloc((size_t)(n + 1) * sizeof(int));
  int*   bktTotal = (int*)  alloc(512 * sizeof(int));
  int*   bktBase  = (int*)  alloc(513 * sizeof(int));
  int*   bktCur   = (int*)  alloc(512 * sizeof(int));
  int*   csr_src  = (int*)  alloc((size_t)(nE + n) * sizeof(int));
  int2*  ebuf     = (int2*) alloc((size_t)nE * sizeof(int2));
  unsigned short* xlb16 = (unsigned short*)alloc((size_t)n * 128 * sizeof(unsigned short));
  unsigned short* xrb16 = (unsigned short*)alloc((size_t)n * 128 * sizeof(unsigned short));
  float* hC       = (float*)alloc((size_t)n * 128 * sizeof(float));
  (void)ws_size; (void)n_in;

  // ---- bucketed CSR build ----
  hipMemsetAsync(bktTotal, 0, 512 * sizeof(int), stream);
  const int eblocks = (nE + 2048 - 1) / 2048;
  p1_bucket_count<<<eblocks, 256, 0, stream>>>(edst, bktTotal, nE, K);
  p2_scan<<<1, 512, 0, stream>>>(bktTotal, bktBase, bktCur, row_off, K, n, nE);
  p3_partition<<<eblocks, 256, 0, stream>>>(esrc, edst, bktCur, ebuf, nE, K);
  p4_build<<<K, 256, 0, stream>>>(ebuf, bktBase, row_off, csr_src, n);

  const int gemm_tiles = (n + 127) / 128;
  const int attn_blocks = (int)(((size_t)n * 16 + 255) / 256);

  // layer 1
  gemm_xlxr_kernel<<<dim3(gemm_tiles, 2), 512, 0, stream>>>(x, Wl[0], bl[0], Wr[0], br[0],
                                                            xlb16, xrb16, n);
  edge_attn_kernel<<<attn_blocks, 256, 0, stream>>>(xlb16, xrb16, row_off, csr_src,
                                                    att[0], bias[0], hC, n, 1);
  // layer 2
  gemm_xlxr_kernel<<<dim3(gemm_tiles, 2), 512, 0, stream>>>(hC, Wl[1], bl[1], Wr[1], br[1],
                                                            xlb16, xrb16, n);
  edge_attn_kernel<<<attn_blocks, 256, 0, stream>>>(xlb16, xrb16, row_off, csr_src,
                                                    att[1], bias[1], hC, n, 1);
  // layer 3
  gemm_xlxr_kernel<<<dim3(gemm_tiles, 2), 512, 0, stream>>>(hC, Wl[2], bl[2], Wr[2], br[2],
                                                            xlb16, xrb16, n);
  edge_attn_kernel<<<attn_blocks, 256, 0, stream>>>(xlb16, xrb16, row_off, csr_src,
                                                    att[2], bias[2], hC, n, 0);

  pool_mlp_kernel<<<n_graphs, 128, 0, stream>>>(hC, batch, n, W4, b4, W5, b5, W6, b6,
                                                (float*)d_out);
}

// Round 8
// 435.291 us; speedup vs baseline: 1.1857x; 1.0530x over previous
//
#include <hip/hip_runtime.h>
#include <hip/hip_bf16.h>
#include <math.h>

#define BK_SHIFT 7            // 128 nodes per bucket
#define BK_NODES 128

typedef _Float16 h2 __attribute__((ext_vector_type(2)));
typedef _Float16 f16x8 __attribute__((ext_vector_type(8)));
typedef float f32x4 __attribute__((ext_vector_type(4)));

__device__ __forceinline__ h2 u2h(unsigned u){ return __builtin_bit_cast(h2, u); }

// ---------------- device helpers ----------------
__device__ __forceinline__ int dev_lower_bound(const int* __restrict__ a, int n, int v){
  int lo = 0, hi = n;
  while (lo < hi){ int mid = (lo + hi) >> 1; if (a[mid] < v) lo = mid + 1; else hi = mid; }
  return lo;
}

// ================= bucketed CSR build =================
__global__ __launch_bounds__(256) void p1_bucket_count(const int* __restrict__ edst,
    int* __restrict__ bktTotal, int nE, int K){
  __shared__ int cnt[512];
  for (int k = threadIdx.x; k < K; k += 256) cnt[k] = 0;
  __syncthreads();
  int i = (blockIdx.x * 256 + threadIdx.x) * 8;
  if (i + 7 < nE){
    int4 a = *(const int4*)(edst + i);
    int4 b = *(const int4*)(edst + i + 4);
    atomicAdd(&cnt[a.x >> BK_SHIFT], 1); atomicAdd(&cnt[a.y >> BK_SHIFT], 1);
    atomicAdd(&cnt[a.z >> BK_SHIFT], 1); atomicAdd(&cnt[a.w >> BK_SHIFT], 1);
    atomicAdd(&cnt[b.x >> BK_SHIFT], 1); atomicAdd(&cnt[b.y >> BK_SHIFT], 1);
    atomicAdd(&cnt[b.z >> BK_SHIFT], 1); atomicAdd(&cnt[b.w >> BK_SHIFT], 1);
  } else {
    for (int j = i; j < nE; ++j) atomicAdd(&cnt[edst[j] >> BK_SHIFT], 1);
  }
  __syncthreads();
  for (int k = threadIdx.x; k < K; k += 256)
    if (cnt[k]) atomicAdd(&bktTotal[k], cnt[k]);
}

__global__ __launch_bounds__(512) void p2_scan(const int* __restrict__ bktTotal,
    int* __restrict__ bktBase, int* __restrict__ bktCur,
    int* __restrict__ row_off, int K, int n, int nE){
  __shared__ int sh[512];
  int t = threadIdx.x;
  int v = (t < K) ? bktTotal[t] : 0;
  sh[t] = v;
  __syncthreads();
  for (int off = 1; off < 512; off <<= 1){
    int u = (t >= off) ? sh[t - off] : 0;
    __syncthreads();
    sh[t] += u;
    __syncthreads();
  }
  if (t < K){
    int excl = sh[t] - v;
    bktBase[t] = excl;
    bktCur[t]  = excl;
  }
  if (t == 0){
    bktBase[K] = nE;
    row_off[n] = nE + n;
  }
}

__global__ __launch_bounds__(256) void p3_partition(const int* __restrict__ esrc,
    const int* __restrict__ edst, int* __restrict__ bktCur,
    int2* __restrict__ ebuf, int nE, int K){
  __shared__ int cnt[512];
  __shared__ int base[512];
  for (int k = threadIdx.x; k < K; k += 256) cnt[k] = 0;
  __syncthreads();
  const int i0 = (blockIdx.x * 256 + threadIdx.x) * 8;
  const int i1 = min(i0 + 8, nE);
  int bkt[8];
  int sv[8], dv[8];
  int cnt_local = i1 - i0;
  for (int j = 0; j < cnt_local; ++j){
    sv[j] = esrc[i0 + j];
    dv[j] = edst[i0 + j];
    bkt[j] = dv[j] >> BK_SHIFT;
    atomicAdd(&cnt[bkt[j]], 1);
  }
  __syncthreads();
  for (int k = threadIdx.x; k < K; k += 256){
    int c = cnt[k];
    base[k] = c ? atomicAdd(&bktCur[k], c) : 0;
  }
  __syncthreads();
  for (int k = threadIdx.x; k < K; k += 256) cnt[k] = 0;
  __syncthreads();
  for (int j = 0; j < cnt_local; ++j){
    int r = atomicAdd(&cnt[bkt[j]], 1);
    ebuf[base[bkt[j]] + r] = make_int2(sv[j], dv[j]);
  }
}

__global__ __launch_bounds__(256) void p4_build(const int2* __restrict__ ebuf,
    const int* __restrict__ bktBase, int* __restrict__ row_off,
    int* __restrict__ csr_src, int n){
  const int b = blockIdx.x;
  const int node0 = b << BK_SHIFT;
  const int nNodes = min(BK_NODES, n - node0);
  const int tid = threadIdx.x;
  __shared__ int ldeg[BK_NODES];
  __shared__ int lcur[BK_NODES];
  __shared__ int sc[BK_NODES];
  const int e0 = bktBase[b];
  const int e1 = bktBase[b + 1];
  if (tid < BK_NODES) ldeg[tid] = 0;
  __syncthreads();
  for (int i = e0 + tid; i < e1; i += 256)
    atomicAdd(&ldeg[ebuf[i].y - node0], 1);
  __syncthreads();
  if (tid < BK_NODES) sc[tid] = (tid < nNodes) ? (ldeg[tid] + 1) : 0;
  __syncthreads();
  for (int off = 1; off < BK_NODES; off <<= 1){
    int u = 0;
    if (tid < BK_NODES && tid >= off) u = sc[tid - off];
    __syncthreads();
    if (tid < BK_NODES) sc[tid] += u;
    __syncthreads();
  }
  if (tid < nNodes){
    const int csr0 = e0 + node0;
    int ro = csr0 + sc[tid] - (ldeg[tid] + 1);
    row_off[node0 + tid] = ro;
    lcur[tid] = ro;
  }
  __syncthreads();
  for (int i = e0 + tid; i < e1; i += 256){
    int2 e = ebuf[i];
    int p = atomicAdd(&lcur[e.y - node0], 1);
    csr_src[p] = e.x;
  }
  __syncthreads();
  if (tid < nNodes)
    csr_src[lcur[tid]] = node0 + tid;
}

// ---------------- W prep: fp32 [k][col] -> f16 transposed [col][k], 6 mats ---
__global__ __launch_bounds__(256) void prep_w_kernel(
    const float* __restrict__ W0, const float* __restrict__ W1,
    const float* __restrict__ W2, const float* __restrict__ W3,
    const float* __restrict__ W4m, const float* __restrict__ W5m,
    unsigned short* __restrict__ Wt16)
{
  const float* Ws[6] = {W0, W1, W2, W3, W4m, W5m};
  const int mat = blockIdx.x >> 3;
  const int chunk = blockIdx.x & 7;
  const float* W = Ws[mat];
  unsigned short* o = Wt16 + mat * 16384;
  #pragma unroll
  for (int e = 0; e < 8; ++e){
    int i = chunk * 2048 + e * 256 + threadIdx.x;
    int k = i >> 7, col = i & 127;
    _Float16 h = (_Float16)W[i];
    o[col * 128 + k] = __builtin_bit_cast(unsigned short, h);
  }
}

// ---------------- MFMA GEMM: out_f16 = f16(X) @ W + b  ----------------------
// 256 thr = 4 waves; block computes 128 rows x 128 cols; K=128; no LDS.
// A-frags (all 2x4) register-resident; B streamed from L2-resident Wt16.
// Layouts (m89-verified): A: row=l&15, k=(l>>4)*8+j ; B: col=l&15, same k ;
// D: col=lane&15, row=(lane>>4)*4+reg.
__global__ __launch_bounds__(256) void gemm_mfma_kernel(
    const float* __restrict__ X,
    const unsigned short* __restrict__ WtL,   // this layer: [2][128col][128k] f16
    const float* __restrict__ bl, const float* __restrict__ br,
    unsigned short* __restrict__ xl16, unsigned short* __restrict__ xr16, int n)
{
  const int mat = blockIdx.y;
  const unsigned short* Wt = WtL + mat * 16384;
  const float* bias = mat ? br : bl;
  unsigned short* out = mat ? xr16 : xl16;
  const int w   = threadIdx.x >> 6;
  const int l   = threadIdx.x & 63;
  const int l15 = l & 15;
  const int kq  = l >> 4;                 // 0..3
  const int rowbase = blockIdx.x * 128 + w * 32;

  f16x8 a[2][4];
  #pragma unroll
  for (int rt = 0; rt < 2; ++rt){
    const int r = rowbase + rt * 16 + l15;
    const bool ok = r < n;
    const float* src = X + (size_t)min(r, n - 1) * 128 + kq * 8;
    #pragma unroll
    for (int ks = 0; ks < 4; ++ks){
      float4 f0 = ok ? *(const float4*)(src + ks * 32)     : make_float4(0.f,0.f,0.f,0.f);
      float4 f1 = ok ? *(const float4*)(src + ks * 32 + 4) : make_float4(0.f,0.f,0.f,0.f);
      f16x8 v;
      v[0] = (_Float16)f0.x; v[1] = (_Float16)f0.y;
      v[2] = (_Float16)f0.z; v[3] = (_Float16)f0.w;
      v[4] = (_Float16)f1.x; v[5] = (_Float16)f1.y;
      v[6] = (_Float16)f1.z; v[7] = (_Float16)f1.w;
      a[rt][ks] = v;
    }
  }

  f32x4 acc[2][8];
  #pragma unroll
  for (int rt = 0; rt < 2; ++rt)
    #pragma unroll
    for (int ct = 0; ct < 8; ++ct)
      acc[rt][ct] = (f32x4){0.f, 0.f, 0.f, 0.f};

  #pragma unroll
  for (int ks = 0; ks < 4; ++ks){
    #pragma unroll
    for (int ct = 0; ct < 8; ++ct){
      f16x8 b = *(const f16x8*)(Wt + (size_t)(ct * 16 + l15) * 128 + ks * 32 + kq * 8);
      acc[0][ct] = __builtin_amdgcn_mfma_f32_16x16x32_f16(a[0][ks], b, acc[0][ct], 0, 0, 0);
      acc[1][ct] = __builtin_amdgcn_mfma_f32_16x16x32_f16(a[1][ks], b, acc[1][ct], 0, 0, 0);
    }
  }

  #pragma unroll
  for (int ct = 0; ct < 8; ++ct){
    const float bv = bias[ct * 16 + l15];
    #pragma unroll
    for (int rt = 0; rt < 2; ++rt){
      #pragma unroll
      for (int rg = 0; rg < 4; ++rg){
        const int r = rowbase + rt * 16 + kq * 4 + rg;
        if (r < n){
          _Float16 h = (_Float16)(acc[rt][ct][rg] + bv);
          out[(size_t)r * 128 + ct * 16 + l15] = __builtin_bit_cast(unsigned short, h);
        }
      }
    }
  }
}

// ---------------- per-destination online-softmax attention ----------------
__global__ __launch_bounds__(256) void edge_attn_kernel(
    const unsigned short* __restrict__ xl16, const unsigned short* __restrict__ xr16,
    const int* __restrict__ row_off, const int* __restrict__ csr_src,
    const float* __restrict__ att, const float* __restrict__ bias,
    float* __restrict__ out, int n, int do_relu)
{
  const int node = (blockIdx.x * blockDim.x + threadIdx.x) >> 4;
  const int nodec = min(node, n - 1);
  const int lane16 = threadIdx.x & 15;
  const int f8 = lane16 * 8;

  const uint4 xru = *(const uint4*)(xr16 + (size_t)nodec * 128 + f8);
  const h2 xr0 = u2h(xru.x), xr1 = u2h(xru.y), xr2 = u2h(xru.z), xr3 = u2h(xru.w);
  const float4 aA = *(const float4*)(att + f8);
  const float4 aB = *(const float4*)(att + f8 + 4);
  const h2 at0 = {(_Float16)aA.x, (_Float16)aA.y};
  const h2 at1 = {(_Float16)aA.z, (_Float16)aA.w};
  const h2 at2 = {(_Float16)aB.x, (_Float16)aB.y};
  const h2 at3 = {(_Float16)aB.z, (_Float16)aB.w};
  const h2 k02 = {(_Float16)0.2f, (_Float16)0.2f};

  const int base = row_off[nodec];
  const int deg  = row_off[nodec + 1] - base;
  int dmax = max(deg, __shfl_xor(deg, 16));
  dmax = max(dmax, __shfl_xor(dmax, 32));

  auto part = [&](uint4 xp) -> float {
    h2 u0 = u2h(xp.x) + xr0;
    h2 u1 = u2h(xp.y) + xr1;
    h2 u2 = u2h(xp.z) + xr2;
    h2 u3 = u2h(xp.w) + xr3;
    u0 = __builtin_elementwise_max(u0, u0 * k02);
    u1 = __builtin_elementwise_max(u1, u1 * k02);
    u2 = __builtin_elementwise_max(u2, u2 * k02);
    u3 = __builtin_elementwise_max(u3, u3 * k02);
    float ps = __builtin_amdgcn_fdot2(u0, at0, 0.f, false);
    ps = __builtin_amdgcn_fdot2(u1, at1, ps, false);
    ps = __builtin_amdgcn_fdot2(u2, at2, ps, false);
    ps = __builtin_amdgcn_fdot2(u3, at3, ps, false);
    return ps;
  };

  uint4 xp = *(const uint4*)(xl16 + (size_t)csr_src[base] * 128 + f8);
  float p = part(xp);
  p += __shfl_xor(p, 1); p += __shfl_xor(p, 2);
  p += __shfl_xor(p, 4); p += __shfl_xor(p, 8);
  float m = p, Mrun = p, s = 1.f;
  float a0 = (float)u2h(xp.x).x, a1 = (float)u2h(xp.x).y;
  float a2 = (float)u2h(xp.y).x, a3 = (float)u2h(xp.y).y;
  float a4 = (float)u2h(xp.z).x, a5 = (float)u2h(xp.z).y;
  float a6 = (float)u2h(xp.w).x, a7 = (float)u2h(xp.w).y;

  for (int it = 1; it < dmax; it += 4){
    const int c0 = min(it,     deg - 1);
    const int c1 = min(it + 1, deg - 1);
    const int c2 = min(it + 2, deg - 1);
    const int c3 = min(it + 3, deg - 1);
    const int s0 = csr_src[base + c0];
    const int s1 = csr_src[base + c1];
    const int s2 = csr_src[base + c2];
    const int s3 = csr_src[base + c3];
    const uint4 xA = *(const uint4*)(xl16 + (size_t)s0 * 128 + f8);
    const uint4 xB = *(const uint4*)(xl16 + (size_t)s1 * 128 + f8);
    const uint4 xC = *(const uint4*)(xl16 + (size_t)s2 * 128 + f8);
    const uint4 xD = *(const uint4*)(xl16 + (size_t)s3 * 128 + f8);
    float pA = part(xA), pB = part(xB), pC = part(xC), pD = part(xD);
    #pragma unroll
    for (int off = 1; off < 16; off <<= 1){
      pA += __shfl_xor(pA, off);
      pB += __shfl_xor(pB, off);
      pC += __shfl_xor(pC, off);
      pD += __shfl_xor(pD, off);
    }
    const bool vA = it < deg, vB = it + 1 < deg, vC = it + 2 < deg, vD = it + 3 < deg;
    float fA = vA ? pA : -3.0e38f;
    float fB = vB ? pB : -3.0e38f;
    float fC = vC ? pC : -3.0e38f;
    float fD = vD ? pD : -3.0e38f;
    Mrun = fmaxf(Mrun, fmaxf(fmaxf(fA, fB), fmaxf(fC, fD)));
    if (__any(Mrun > m + 8.f)){
      float sc = __expf(m - Mrun);
      s *= sc;
      a0 *= sc; a1 *= sc; a2 *= sc; a3 *= sc;
      a4 *= sc; a5 *= sc; a6 *= sc; a7 *= sc;
      m = Mrun;
    }
    float qA = vA ? __expf(pA - m) : 0.f;
    float qB = vB ? __expf(pB - m) : 0.f;
    float qC = vC ? __expf(pC - m) : 0.f;
    float qD = vD ? __expf(pD - m) : 0.f;
    s += (qA + qB) + (qC + qD);
    h2 w;
    w = u2h(xA.x); a0 = fmaf(qA, (float)w.x, a0); a1 = fmaf(qA, (float)w.y, a1);
    w = u2h(xA.y); a2 = fmaf(qA, (float)w.x, a2); a3 = fmaf(qA, (float)w.y, a3);
    w = u2h(xA.z); a4 = fmaf(qA, (float)w.x, a4); a5 = fmaf(qA, (float)w.y, a5);
    w = u2h(xA.w); a6 = fmaf(qA, (float)w.x, a6); a7 = fmaf(qA, (float)w.y, a7);
    w = u2h(xB.x); a0 = fmaf(qB, (float)w.x, a0); a1 = fmaf(qB, (float)w.y, a1);
    w = u2h(xB.y); a2 = fmaf(qB, (float)w.x, a2); a3 = fmaf(qB, (float)w.y, a3);
    w = u2h(xB.z); a4 = fmaf(qB, (float)w.x, a4); a5 = fmaf(qB, (float)w.y, a5);
    w = u2h(xB.w); a6 = fmaf(qB, (float)w.x, a6); a7 = fmaf(qB, (float)w.y, a7);
    w = u2h(xC.x); a0 = fmaf(qC, (float)w.x, a0); a1 = fmaf(qC, (float)w.y, a1);
    w = u2h(xC.y); a2 = fmaf(qC, (float)w.x, a2); a3 = fmaf(qC, (float)w.y, a3);
    w = u2h(xC.z); a4 = fmaf(qC, (float)w.x, a4); a5 = fmaf(qC, (float)w.y, a5);
    w = u2h(xC.w); a6 = fmaf(qC, (float)w.x, a6); a7 = fmaf(qC, (float)w.y, a7);
    w = u2h(xD.x); a0 = fmaf(qD, (float)w.x, a0); a1 = fmaf(qD, (float)w.y, a1);
    w = u2h(xD.y); a2 = fmaf(qD, (float)w.x, a2); a3 = fmaf(qD, (float)w.y, a3);
    w = u2h(xD.z); a4 = fmaf(qD, (float)w.x, a4); a5 = fmaf(qD, (float)w.y, a5);
    w = u2h(xD.w); a6 = fmaf(qD, (float)w.x, a6); a7 = fmaf(qD, (float)w.y, a7);
  }

  if (node < n){
    const float inv = 1.0f / s;
    const float4 bA = *(const float4*)(bias + f8);
    const float4 bB = *(const float4*)(bias + f8 + 4);
    float o0 = fmaf(a0, inv, bA.x), o1 = fmaf(a1, inv, bA.y);
    float o2 = fmaf(a2, inv, bA.z), o3 = fmaf(a3, inv, bA.w);
    float o4 = fmaf(a4, inv, bB.x), o5 = fmaf(a5, inv, bB.y);
    float o6 = fmaf(a6, inv, bB.z), o7 = fmaf(a7, inv, bB.w);
    if (do_relu){
      o0 = fmaxf(o0, 0.f); o1 = fmaxf(o1, 0.f); o2 = fmaxf(o2, 0.f); o3 = fmaxf(o3, 0.f);
      o4 = fmaxf(o4, 0.f); o5 = fmaxf(o5, 0.f); o6 = fmaxf(o6, 0.f); o7 = fmaxf(o7, 0.f);
    }
    *(float4*)(out + (size_t)node * 128 + f8)     = make_float4(o0, o1, o2, o3);
    *(float4*)(out + (size_t)node * 128 + f8 + 4) = make_float4(o4, o5, o6, o7);
  }
}

// ---------------- mean-pool + MLP head ----------------
__global__ __launch_bounds__(128) void pool_mlp_kernel(
    const float* __restrict__ h, const int* __restrict__ batch, int n,
    const float* __restrict__ W4, const float* __restrict__ b4,
    const float* __restrict__ W5, const float* __restrict__ b5,
    const float* __restrict__ W6, const float* __restrict__ b6,
    float* __restrict__ out)
{
  int g = blockIdx.x;
  int t = threadIdx.x;
  __shared__ float gf[128];
  __shared__ float h1[128];
  __shared__ float h2s[64];
  int lo = dev_lower_bound(batch, n, g);
  int hi = dev_lower_bound(batch, n, g + 1);
  float ssum = 0.f;
  for (int i = lo; i < hi; ++i) ssum += h[(size_t)i * 128 + t];
  float cnt = (float)(hi - lo);
  gf[t] = ssum / fmaxf(cnt, 1.0f);
  __syncthreads();
  float a = b4[t];
  for (int k = 0; k < 128; ++k) a = fmaf(gf[k], W4[k * 128 + t], a);
  h1[t] = 1.0f / (1.0f + __expf(-a));
  __syncthreads();
  if (t < 64){
    float a5 = b5[t];
    for (int k = 0; k < 128; ++k) a5 = fmaf(h1[k], W5[k * 64 + t], a5);
    h2s[t] = 1.0f / (1.0f + __expf(-a5));
  }
  __syncthreads();
  if (t < 2){
    float a6 = b6[t];
    for (int k = 0; k < 64; ++k) a6 = fmaf(h2s[k], W6[k * 2 + t], a6);
    out[g * 2 + t] = a6;
  }
}

// ---------------- launcher ----------------
extern "C" void kernel_launch(void* const* d_in, const int* in_sizes, int n_in,
                              void* d_out, int out_size, void* d_ws, size_t ws_size,
                              hipStream_t stream)
{
  const float* x          = (const float*)d_in[0];
  const int*   edge_index = (const int*)d_in[1];
  const int*   batch      = (const int*)d_in[2];
  const int n  = in_sizes[0] / 128;            // 50000
  const int nE = in_sizes[1] / 2;              // 1600000
  const int* esrc = edge_index;
  const int* edst = edge_index + nE;
  const int n_graphs = out_size / 2;           // 512
  const int K = (n + BK_NODES - 1) >> BK_SHIFT;

  const float *Wl[3], *bl[3], *Wr[3], *br[3], *att[3], *bias[3];
  for (int l = 0; l < 3; ++l){
    Wl[l]   = (const float*)d_in[3 + 6 * l + 0];
    bl[l]   = (const float*)d_in[3 + 6 * l + 1];
    Wr[l]   = (const float*)d_in[3 + 6 * l + 2];
    br[l]   = (const float*)d_in[3 + 6 * l + 3];
    att[l]  = (const float*)d_in[3 + 6 * l + 4];
    bias[l] = (const float*)d_in[3 + 6 * l + 5];
  }
  const float* W4 = (const float*)d_in[21]; const float* b4 = (const float*)d_in[22];
  const float* W5 = (const float*)d_in[23]; const float* b5 = (const float*)d_in[24];
  const float* W6 = (const float*)d_in[25]; const float* b6 = (const float*)d_in[26];

  char* ws = (char*)d_ws;
  size_t off = 0;
  auto alloc = [&](size_t bytes) -> void* {
    void* p = ws + off;
    off = (off + bytes + 255) & ~(size_t)255;
    return p;
  };
  int*   row_off  = (int*)  alloc((size_t)(n + 1) * sizeof(int));
  int*   bktTotal = (int*)  alloc(512 * sizeof(int));
  int*   bktBase  = (int*)  alloc(513 * sizeof(int));
  int*   bktCur   = (int*)  alloc(512 * sizeof(int));
  int*   csr_src  = (int*)  alloc((size_t)(nE + n) * sizeof(int));
  int2*  ebuf     = (int2*) alloc((size_t)nE * sizeof(int2));
  unsigned short* xlb16 = (unsigned short*)alloc((size_t)n * 128 * sizeof(unsigned short));
  unsigned short* xrb16 = (unsigned short*)alloc((size_t)n * 128 * sizeof(unsigned short));
  unsigned short* Wt16  = (unsigned short*)alloc(6 * 16384 * sizeof(unsigned short));
  float* hC       = (float*)alloc((size_t)n * 128 * sizeof(float));
  (void)ws_size; (void)n_in;

  // ---- W prep (f16 transpose, all 6 matrices) ----
  prep_w_kernel<<<48, 256, 0, stream>>>(Wl[0], Wr[0], Wl[1], Wr[1], Wl[2], Wr[2], Wt16);

  // ---- bucketed CSR build ----
  hipMemsetAsync(bktTotal, 0, 512 * sizeof(int), stream);
  const int eblocks = (nE + 2048 - 1) / 2048;
  p1_bucket_count<<<eblocks, 256, 0, stream>>>(edst, bktTotal, nE, K);
  p2_scan<<<1, 512, 0, stream>>>(bktTotal, bktBase, bktCur, row_off, K, n, nE);
  p3_partition<<<eblocks, 256, 0, stream>>>(esrc, edst, bktCur, ebuf, nE, K);
  p4_build<<<K, 256, 0, stream>>>(ebuf, bktBase, row_off, csr_src, n);

  const int gemm_tiles = (n + 127) / 128;
  const int attn_blocks = (int)(((size_t)n * 16 + 255) / 256);

  // layer 1
  gemm_mfma_kernel<<<dim3(gemm_tiles, 2), 256, 0, stream>>>(x, Wt16 + 0 * 32768,
                                                            bl[0], br[0], xlb16, xrb16, n);
  edge_attn_kernel<<<attn_blocks, 256, 0, stream>>>(xlb16, xrb16, row_off, csr_src,
                                                    att[0], bias[0], hC, n, 1);
  // layer 2
  gemm_mfma_kernel<<<dim3(gemm_tiles, 2), 256, 0, stream>>>(hC, Wt16 + 1 * 32768,
                                                            bl[1], br[1], xlb16, xrb16, n);
  edge_attn_kernel<<<attn_blocks, 256, 0, stream>>>(xlb16, xrb16, row_off, csr_src,
                                                    att[1], bias[1], hC, n, 1);
  // layer 3
  gemm_mfma_kernel<<<dim3(gemm_tiles, 2), 256, 0, stream>>>(hC, Wt16 + 2 * 32768,
                                                            bl[2], br[2], xlb16, xrb16, n);
  edge_attn_kernel<<<attn_blocks, 256, 0, stream>>>(xlb16, xrb16, row_off, csr_src,
                                                    att[2], bias[2], hC, n, 0);

  pool_mlp_kernel<<<n_graphs, 128, 0, stream>>>(hC, batch, n, W4, b4, W5, b5, W6, b6,
                                                (float*)d_out);
}

// Round 9
// 431.781 us; speedup vs baseline: 1.1953x; 1.0081x over previous
//
#include <hip/hip_runtime.h>
#include <hip/hip_bf16.h>
#include <math.h>

#define BK_SHIFT 7            // 128 nodes per bucket
#define BK_NODES 128

typedef _Float16 h2 __attribute__((ext_vector_type(2)));
typedef _Float16 f16x8 __attribute__((ext_vector_type(8)));
typedef float f32x4 __attribute__((ext_vector_type(4)));

__device__ __forceinline__ h2 u2h(unsigned u){ return __builtin_bit_cast(h2, u); }

// ---------------- device helpers ----------------
__device__ __forceinline__ int dev_lower_bound(const int* __restrict__ a, int n, int v){
  int lo = 0, hi = n;
  while (lo < hi){ int mid = (lo + hi) >> 1; if (a[mid] < v) lo = mid + 1; else hi = mid; }
  return lo;
}

// ================= bucketed CSR build =================
__global__ __launch_bounds__(256) void p1_bucket_count(const int* __restrict__ edst,
    int* __restrict__ bktTotal, int nE, int K){
  __shared__ int cnt[512];
  for (int k = threadIdx.x; k < K; k += 256) cnt[k] = 0;
  __syncthreads();
  int i = (blockIdx.x * 256 + threadIdx.x) * 8;
  if (i + 7 < nE){
    int4 a = *(const int4*)(edst + i);
    int4 b = *(const int4*)(edst + i + 4);
    atomicAdd(&cnt[a.x >> BK_SHIFT], 1); atomicAdd(&cnt[a.y >> BK_SHIFT], 1);
    atomicAdd(&cnt[a.z >> BK_SHIFT], 1); atomicAdd(&cnt[a.w >> BK_SHIFT], 1);
    atomicAdd(&cnt[b.x >> BK_SHIFT], 1); atomicAdd(&cnt[b.y >> BK_SHIFT], 1);
    atomicAdd(&cnt[b.z >> BK_SHIFT], 1); atomicAdd(&cnt[b.w >> BK_SHIFT], 1);
  } else {
    for (int j = i; j < nE; ++j) atomicAdd(&cnt[edst[j] >> BK_SHIFT], 1);
  }
  __syncthreads();
  for (int k = threadIdx.x; k < K; k += 256)
    if (cnt[k]) atomicAdd(&bktTotal[k], cnt[k]);
}

__global__ __launch_bounds__(512) void p2_scan(const int* __restrict__ bktTotal,
    int* __restrict__ bktBase, int* __restrict__ bktCur,
    int* __restrict__ row_off, int K, int n, int nE){
  __shared__ int sh[512];
  int t = threadIdx.x;
  int v = (t < K) ? bktTotal[t] : 0;
  sh[t] = v;
  __syncthreads();
  for (int off = 1; off < 512; off <<= 1){
    int u = (t >= off) ? sh[t - off] : 0;
    __syncthreads();
    sh[t] += u;
    __syncthreads();
  }
  if (t < K){
    int excl = sh[t] - v;
    bktBase[t] = excl;
    bktCur[t]  = excl;
  }
  if (t == 0){
    bktBase[K] = nE;
    row_off[n] = nE + n;
  }
}

__global__ __launch_bounds__(256) void p3_partition(const int* __restrict__ esrc,
    const int* __restrict__ edst, int* __restrict__ bktCur,
    int2* __restrict__ ebuf, int nE, int K){
  __shared__ int cnt[512];
  __shared__ int base[512];
  for (int k = threadIdx.x; k < K; k += 256) cnt[k] = 0;
  __syncthreads();
  const int i0 = (blockIdx.x * 256 + threadIdx.x) * 8;
  const int i1 = min(i0 + 8, nE);
  int bkt[8];
  int sv[8], dv[8];
  int cnt_local = i1 - i0;
  for (int j = 0; j < cnt_local; ++j){
    sv[j] = esrc[i0 + j];
    dv[j] = edst[i0 + j];
    bkt[j] = dv[j] >> BK_SHIFT;
    atomicAdd(&cnt[bkt[j]], 1);
  }
  __syncthreads();
  for (int k = threadIdx.x; k < K; k += 256){
    int c = cnt[k];
    base[k] = c ? atomicAdd(&bktCur[k], c) : 0;
  }
  __syncthreads();
  for (int k = threadIdx.x; k < K; k += 256) cnt[k] = 0;
  __syncthreads();
  for (int j = 0; j < cnt_local; ++j){
    int r = atomicAdd(&cnt[bkt[j]], 1);
    ebuf[base[bkt[j]] + r] = make_int2(sv[j], dv[j]);
  }
}

__global__ __launch_bounds__(256) void p4_build(const int2* __restrict__ ebuf,
    const int* __restrict__ bktBase, int* __restrict__ row_off,
    int* __restrict__ csr_src, int n){
  const int b = blockIdx.x;
  const int node0 = b << BK_SHIFT;
  const int nNodes = min(BK_NODES, n - node0);
  const int tid = threadIdx.x;
  __shared__ int ldeg[BK_NODES];
  __shared__ int lcur[BK_NODES];
  __shared__ int sc[BK_NODES];
  const int e0 = bktBase[b];
  const int e1 = bktBase[b + 1];
  if (tid < BK_NODES) ldeg[tid] = 0;
  __syncthreads();
  for (int i = e0 + tid; i < e1; i += 256)
    atomicAdd(&ldeg[ebuf[i].y - node0], 1);
  __syncthreads();
  if (tid < BK_NODES) sc[tid] = (tid < nNodes) ? (ldeg[tid] + 1) : 0;
  __syncthreads();
  for (int off = 1; off < BK_NODES; off <<= 1){
    int u = 0;
    if (tid < BK_NODES && tid >= off) u = sc[tid - off];
    __syncthreads();
    if (tid < BK_NODES) sc[tid] += u;
    __syncthreads();
  }
  if (tid < nNodes){
    const int csr0 = e0 + node0;
    int ro = csr0 + sc[tid] - (ldeg[tid] + 1);
    row_off[node0 + tid] = ro;
    lcur[tid] = ro;
  }
  __syncthreads();
  for (int i = e0 + tid; i < e1; i += 256){
    int2 e = ebuf[i];
    int p = atomicAdd(&lcur[e.y - node0], 1);
    csr_src[p] = e.x;
  }
  __syncthreads();
  if (tid < nNodes)
    csr_src[lcur[tid]] = node0 + tid;
}

// ================= degree sort (counting sort, 256 bins) =================
__global__ __launch_bounds__(256) void deg_hist(const int* __restrict__ row_off,
    int* __restrict__ dbins, int n){
  __shared__ int cnt[256];
  cnt[threadIdx.x] = 0;
  __syncthreads();
  int i = blockIdx.x * 256 + threadIdx.x;
  if (i < n){
    int deg = row_off[i + 1] - row_off[i];
    atomicAdd(&cnt[min(deg, 255)], 1);
  }
  __syncthreads();
  if (cnt[threadIdx.x]) atomicAdd(&dbins[threadIdx.x], cnt[threadIdx.x]);
}

__global__ __launch_bounds__(256) void deg_scan(const int* __restrict__ dbins,
    int* __restrict__ dcur){
  __shared__ int sh[256];
  int t = threadIdx.x;
  int v = dbins[t];
  sh[t] = v;
  __syncthreads();
  for (int off = 1; off < 256; off <<= 1){
    int u = (t >= off) ? sh[t - off] : 0;
    __syncthreads();
    sh[t] += u;
    __syncthreads();
  }
  dcur[t] = sh[t] - v;               // exclusive
}

__global__ __launch_bounds__(256) void deg_scatter(const int* __restrict__ row_off,
    int* __restrict__ dcur, int* __restrict__ order, int n){
  __shared__ int cnt[256];
  __shared__ int base[256];
  cnt[threadIdx.x] = 0;
  __syncthreads();
  int i = blockIdx.x * 256 + threadIdx.x;
  int bin = 0, r = 0;
  if (i < n){
    int deg = row_off[i + 1] - row_off[i];
    bin = min(deg, 255);
    r = atomicAdd(&cnt[bin], 1);
  }
  __syncthreads();
  base[threadIdx.x] = cnt[threadIdx.x] ? atomicAdd(&dcur[threadIdx.x], cnt[threadIdx.x]) : 0;
  __syncthreads();
  if (i < n) order[base[bin] + r] = i;
}

// ---------------- W prep: fp32 [k][col] -> f16 transposed [col][k], 6 mats ---
__global__ __launch_bounds__(256) void prep_w_kernel(
    const float* __restrict__ W0, const float* __restrict__ W1,
    const float* __restrict__ W2, const float* __restrict__ W3,
    const float* __restrict__ W4m, const float* __restrict__ W5m,
    unsigned short* __restrict__ Wt16)
{
  const float* Ws[6] = {W0, W1, W2, W3, W4m, W5m};
  const int mat = blockIdx.x >> 3;
  const int chunk = blockIdx.x & 7;
  const float* W = Ws[mat];
  unsigned short* o = Wt16 + mat * 16384;
  #pragma unroll
  for (int e = 0; e < 8; ++e){
    int i = chunk * 2048 + e * 256 + threadIdx.x;
    int k = i >> 7, col = i & 127;
    _Float16 h = (_Float16)W[i];
    o[col * 128 + k] = __builtin_bit_cast(unsigned short, h);
  }
}

// ---------------- MFMA GEMM: out_f16 = f16(X) @ W + b  ----------------------
template<bool F16IN>
__global__ __launch_bounds__(256) void gemm_mfma_kernel(
    const void* __restrict__ Xv,
    const unsigned short* __restrict__ WtL,   // this layer: [2][128col][128k] f16
    const float* __restrict__ bl, const float* __restrict__ br,
    unsigned short* __restrict__ xl16, unsigned short* __restrict__ xr16, int n)
{
  const int mat = blockIdx.y;
  const unsigned short* Wt = WtL + mat * 16384;
  const float* bias = mat ? br : bl;
  unsigned short* out = mat ? xr16 : xl16;
  const int w   = threadIdx.x >> 6;
  const int l   = threadIdx.x & 63;
  const int l15 = l & 15;
  const int kq  = l >> 4;                 // 0..3
  const int rowbase = blockIdx.x * 128 + w * 32;

  f16x8 a[2][4];
  #pragma unroll
  for (int rt = 0; rt < 2; ++rt){
    const int r = rowbase + rt * 16 + l15;
    const bool ok = r < n;
    const int rc = min(r, n - 1);
    #pragma unroll
    for (int ks = 0; ks < 4; ++ks){
      if (F16IN){
        const unsigned short* src = (const unsigned short*)Xv + (size_t)rc * 128 + kq * 8 + ks * 32;
        f16x8 v = ok ? *(const f16x8*)src : (f16x8){0,0,0,0,0,0,0,0};
        a[rt][ks] = v;
      } else {
        const float* src = (const float*)Xv + (size_t)rc * 128 + kq * 8 + ks * 32;
        float4 f0 = ok ? *(const float4*)(src)     : make_float4(0.f,0.f,0.f,0.f);
        float4 f1 = ok ? *(const float4*)(src + 4) : make_float4(0.f,0.f,0.f,0.f);
        f16x8 v;
        v[0] = (_Float16)f0.x; v[1] = (_Float16)f0.y;
        v[2] = (_Float16)f0.z; v[3] = (_Float16)f0.w;
        v[4] = (_Float16)f1.x; v[5] = (_Float16)f1.y;
        v[6] = (_Float16)f1.z; v[7] = (_Float16)f1.w;
        a[rt][ks] = v;
      }
    }
  }

  f32x4 acc[2][8];
  #pragma unroll
  for (int rt = 0; rt < 2; ++rt)
    #pragma unroll
    for (int ct = 0; ct < 8; ++ct)
      acc[rt][ct] = (f32x4){0.f, 0.f, 0.f, 0.f};

  #pragma unroll
  for (int ks = 0; ks < 4; ++ks){
    #pragma unroll
    for (int ct = 0; ct < 8; ++ct){
      f16x8 b = *(const f16x8*)(Wt + (size_t)(ct * 16 + l15) * 128 + ks * 32 + kq * 8);
      acc[0][ct] = __builtin_amdgcn_mfma_f32_16x16x32_f16(a[0][ks], b, acc[0][ct], 0, 0, 0);
      acc[1][ct] = __builtin_amdgcn_mfma_f32_16x16x32_f16(a[1][ks], b, acc[1][ct], 0, 0, 0);
    }
  }

  #pragma unroll
  for (int ct = 0; ct < 8; ++ct){
    const float bv = bias[ct * 16 + l15];
    #pragma unroll
    for (int rt = 0; rt < 2; ++rt){
      #pragma unroll
      for (int rg = 0; rg < 4; ++rg){
        const int r = rowbase + rt * 16 + kq * 4 + rg;
        if (r < n){
          _Float16 h = (_Float16)(acc[rt][ct][rg] + bv);
          out[(size_t)r * 128 + ct * 16 + l15] = __builtin_bit_cast(unsigned short, h);
        }
      }
    }
  }
}

// ---------------- per-destination online-softmax attention ----------------
// Degree-sorted order: co-scheduled quarters have ~equal degree. f16 output.
__global__ __launch_bounds__(256) void edge_attn_kernel(
    const unsigned short* __restrict__ xl16, const unsigned short* __restrict__ xr16,
    const int* __restrict__ row_off, const int* __restrict__ csr_src,
    const int* __restrict__ order,
    const float* __restrict__ att, const float* __restrict__ bias,
    unsigned short* __restrict__ out16, int n, int do_relu)
{
  const int gid = (blockIdx.x * blockDim.x + threadIdx.x) >> 4;
  const int node = order[min(gid, n - 1)];
  const int lane16 = threadIdx.x & 15;
  const int f8 = lane16 * 8;

  const uint4 xru = *(const uint4*)(xr16 + (size_t)node * 128 + f8);
  const h2 xr0 = u2h(xru.x), xr1 = u2h(xru.y), xr2 = u2h(xru.z), xr3 = u2h(xru.w);
  const float4 aA = *(const float4*)(att + f8);
  const float4 aB = *(const float4*)(att + f8 + 4);
  const h2 at0 = {(_Float16)aA.x, (_Float16)aA.y};
  const h2 at1 = {(_Float16)aA.z, (_Float16)aA.w};
  const h2 at2 = {(_Float16)aB.x, (_Float16)aB.y};
  const h2 at3 = {(_Float16)aB.z, (_Float16)aB.w};
  const h2 k02 = {(_Float16)0.2f, (_Float16)0.2f};

  const int base = row_off[node];
  const int deg  = row_off[node + 1] - base;
  int dmax = max(deg, __shfl_xor(deg, 16));
  dmax = max(dmax, __shfl_xor(dmax, 32));

  auto part = [&](uint4 xp) -> float {
    h2 u0 = u2h(xp.x) + xr0;
    h2 u1 = u2h(xp.y) + xr1;
    h2 u2 = u2h(xp.z) + xr2;
    h2 u3 = u2h(xp.w) + xr3;
    u0 = __builtin_elementwise_max(u0, u0 * k02);
    u1 = __builtin_elementwise_max(u1, u1 * k02);
    u2 = __builtin_elementwise_max(u2, u2 * k02);
    u3 = __builtin_elementwise_max(u3, u3 * k02);
    float ps = __builtin_amdgcn_fdot2(u0, at0, 0.f, false);
    ps = __builtin_amdgcn_fdot2(u1, at1, ps, false);
    ps = __builtin_amdgcn_fdot2(u2, at2, ps, false);
    ps = __builtin_amdgcn_fdot2(u3, at3, ps, false);
    return ps;
  };

  uint4 xp = *(const uint4*)(xl16 + (size_t)csr_src[base] * 128 + f8);
  float p = part(xp);
  p += __shfl_xor(p, 1); p += __shfl_xor(p, 2);
  p += __shfl_xor(p, 4); p += __shfl_xor(p, 8);
  float m = p, Mrun = p, s = 1.f;
  float a0 = (float)u2h(xp.x).x, a1 = (float)u2h(xp.x).y;
  float a2 = (float)u2h(xp.y).x, a3 = (float)u2h(xp.y).y;
  float a4 = (float)u2h(xp.z).x, a5 = (float)u2h(xp.z).y;
  float a6 = (float)u2h(xp.w).x, a7 = (float)u2h(xp.w).y;

  for (int it = 1; it < dmax; it += 4){
    const int c0 = min(it,     deg - 1);
    const int c1 = min(it + 1, deg - 1);
    const int c2 = min(it + 2, deg - 1);
    const int c3 = min(it + 3, deg - 1);
    const int s0 = csr_src[base + c0];
    const int s1 = csr_src[base + c1];
    const int s2 = csr_src[base + c2];
    const int s3 = csr_src[base + c3];
    const uint4 xA = *(const uint4*)(xl16 + (size_t)s0 * 128 + f8);
    const uint4 xB = *(const uint4*)(xl16 + (size_t)s1 * 128 + f8);
    const uint4 xC = *(const uint4*)(xl16 + (size_t)s2 * 128 + f8);
    const uint4 xD = *(const uint4*)(xl16 + (size_t)s3 * 128 + f8);
    float pA = part(xA), pB = part(xB), pC = part(xC), pD = part(xD);
    #pragma unroll
    for (int off = 1; off < 16; off <<= 1){
      pA += __shfl_xor(pA, off);
      pB += __shfl_xor(pB, off);
      pC += __shfl_xor(pC, off);
      pD += __shfl_xor(pD, off);
    }
    const bool vA = it < deg, vB = it + 1 < deg, vC = it + 2 < deg, vD = it + 3 < deg;
    float fA = vA ? pA : -3.0e38f;
    float fB = vB ? pB : -3.0e38f;
    float fC = vC ? pC : -3.0e38f;
    float fD = vD ? pD : -3.0e38f;
    Mrun = fmaxf(Mrun, fmaxf(fmaxf(fA, fB), fmaxf(fC, fD)));
    if (__any(Mrun > m + 8.f)){
      float sc = __expf(m - Mrun);
      s *= sc;
      a0 *= sc; a1 *= sc; a2 *= sc; a3 *= sc;
      a4 *= sc; a5 *= sc; a6 *= sc; a7 *= sc;
      m = Mrun;
    }
    float qA = vA ? __expf(pA - m) : 0.f;
    float qB = vB ? __expf(pB - m) : 0.f;
    float qC = vC ? __expf(pC - m) : 0.f;
    float qD = vD ? __expf(pD - m) : 0.f;
    s += (qA + qB) + (qC + qD);
    h2 w;
    w = u2h(xA.x); a0 = fmaf(qA, (float)w.x, a0); a1 = fmaf(qA, (float)w.y, a1);
    w = u2h(xA.y); a2 = fmaf(qA, (float)w.x, a2); a3 = fmaf(qA, (float)w.y, a3);
    w = u2h(xA.z); a4 = fmaf(qA, (float)w.x, a4); a5 = fmaf(qA, (float)w.y, a5);
    w = u2h(xA.w); a6 = fmaf(qA, (float)w.x, a6); a7 = fmaf(qA, (float)w.y, a7);
    w = u2h(xB.x); a0 = fmaf(qB, (float)w.x, a0); a1 = fmaf(qB, (float)w.y, a1);
    w = u2h(xB.y); a2 = fmaf(qB, (float)w.x, a2); a3 = fmaf(qB, (float)w.y, a3);
    w = u2h(xB.z); a4 = fmaf(qB, (float)w.x, a4); a5 = fmaf(qB, (float)w.y, a5);
    w = u2h(xB.w); a6 = fmaf(qB, (float)w.x, a6); a7 = fmaf(qB, (float)w.y, a7);
    w = u2h(xC.x); a0 = fmaf(qC, (float)w.x, a0); a1 = fmaf(qC, (float)w.y, a1);
    w = u2h(xC.y); a2 = fmaf(qC, (float)w.x, a2); a3 = fmaf(qC, (float)w.y, a3);
    w = u2h(xC.z); a4 = fmaf(qC, (float)w.x, a4); a5 = fmaf(qC, (float)w.y, a5);
    w = u2h(xC.w); a6 = fmaf(qC, (float)w.x, a6); a7 = fmaf(qC, (float)w.y, a7);
    w = u2h(xD.x); a0 = fmaf(qD, (float)w.x, a0); a1 = fmaf(qD, (float)w.y, a1);
    w = u2h(xD.y); a2 = fmaf(qD, (float)w.x, a2); a3 = fmaf(qD, (float)w.y, a3);
    w = u2h(xD.z); a4 = fmaf(qD, (float)w.x, a4); a5 = fmaf(qD, (float)w.y, a5);
    w = u2h(xD.w); a6 = fmaf(qD, (float)w.x, a6); a7 = fmaf(qD, (float)w.y, a7);
  }

  if (gid < n){
    const float inv = 1.0f / s;
    const float4 bA = *(const float4*)(bias + f8);
    const float4 bB = *(const float4*)(bias + f8 + 4);
    float o0 = fmaf(a0, inv, bA.x), o1 = fmaf(a1, inv, bA.y);
    float o2 = fmaf(a2, inv, bA.z), o3 = fmaf(a3, inv, bA.w);
    float o4 = fmaf(a4, inv, bB.x), o5 = fmaf(a5, inv, bB.y);
    float o6 = fmaf(a6, inv, bB.z), o7 = fmaf(a7, inv, bB.w);
    if (do_relu){
      o0 = fmaxf(o0, 0.f); o1 = fmaxf(o1, 0.f); o2 = fmaxf(o2, 0.f); o3 = fmaxf(o3, 0.f);
      o4 = fmaxf(o4, 0.f); o5 = fmaxf(o5, 0.f); o6 = fmaxf(o6, 0.f); o7 = fmaxf(o7, 0.f);
    }
    ushort4 wlo, whi;
    wlo.x = __builtin_bit_cast(unsigned short, (_Float16)o0);
    wlo.y = __builtin_bit_cast(unsigned short, (_Float16)o1);
    wlo.z = __builtin_bit_cast(unsigned short, (_Float16)o2);
    wlo.w = __builtin_bit_cast(unsigned short, (_Float16)o3);
    whi.x = __builtin_bit_cast(unsigned short, (_Float16)o4);
    whi.y = __builtin_bit_cast(unsigned short, (_Float16)o5);
    whi.z = __builtin_bit_cast(unsigned short, (_Float16)o6);
    whi.w = __builtin_bit_cast(unsigned short, (_Float16)o7);
    *(ushort4*)(out16 + (size_t)node * 128 + f8)     = wlo;
    *(ushort4*)(out16 + (size_t)node * 128 + f8 + 4) = whi;
  }
}

// ---------------- mean-pool + MLP head (f16 h input) ----------------
__global__ __launch_bounds__(128) void pool_mlp_kernel(
    const unsigned short* __restrict__ h, const int* __restrict__ batch, int n,
    const float* __restrict__ W4, const float* __restrict__ b4,
    const float* __restrict__ W5, const float* __restrict__ b5,
    const float* __restrict__ W6, const float* __restrict__ b6,
    float* __restrict__ out)
{
  int g = blockIdx.x;
  int t = threadIdx.x;
  __shared__ float gf[128];
  __shared__ float h1[128];
  __shared__ float h2s[64];
  int lo = dev_lower_bound(batch, n, g);
  int hi = dev_lower_bound(batch, n, g + 1);
  float ssum = 0.f;
  for (int i = lo; i < hi; ++i){
    _Float16 hv = __builtin_bit_cast(_Float16, h[(size_t)i * 128 + t]);
    ssum += (float)hv;
  }
  float cnt = (float)(hi - lo);
  gf[t] = ssum / fmaxf(cnt, 1.0f);
  __syncthreads();
  float a = b4[t];
  for (int k = 0; k < 128; ++k) a = fmaf(gf[k], W4[k * 128 + t], a);
  h1[t] = 1.0f / (1.0f + __expf(-a));
  __syncthreads();
  if (t < 64){
    float a5 = b5[t];
    for (int k = 0; k < 128; ++k) a5 = fmaf(h1[k], W5[k * 64 + t], a5);
    h2s[t] = 1.0f / (1.0f + __expf(-a5));
  }
  __syncthreads();
  if (t < 2){
    float a6 = b6[t];
    for (int k = 0; k < 64; ++k) a6 = fmaf(h2s[k], W6[k * 2 + t], a6);
    out[g * 2 + t] = a6;
  }
}

// ---------------- launcher ----------------
extern "C" void kernel_launch(void* const* d_in, const int* in_sizes, int n_in,
                              void* d_out, int out_size, void* d_ws, size_t ws_size,
                              hipStream_t stream)
{
  const float* x          = (const float*)d_in[0];
  const int*   edge_index = (const int*)d_in[1];
  const int*   batch      = (const int*)d_in[2];
  const int n  = in_sizes[0] / 128;            // 50000
  const int nE = in_sizes[1] / 2;              // 1600000
  const int* esrc = edge_index;
  const int* edst = edge_index + nE;
  const int n_graphs = out_size / 2;           // 512
  const int K = (n + BK_NODES - 1) >> BK_SHIFT;

  const float *Wl[3], *bl[3], *Wr[3], *br[3], *att[3], *bias[3];
  for (int l = 0; l < 3; ++l){
    Wl[l]   = (const float*)d_in[3 + 6 * l + 0];
    bl[l]   = (const float*)d_in[3 + 6 * l + 1];
    Wr[l]   = (const float*)d_in[3 + 6 * l + 2];
    br[l]   = (const float*)d_in[3 + 6 * l + 3];
    att[l]  = (const float*)d_in[3 + 6 * l + 4];
    bias[l] = (const float*)d_in[3 + 6 * l + 5];
  }
  const float* W4 = (const float*)d_in[21]; const float* b4 = (const float*)d_in[22];
  const float* W5 = (const float*)d_in[23]; const float* b5 = (const float*)d_in[24];
  const float* W6 = (const float*)d_in[25]; const float* b6 = (const float*)d_in[26];

  char* ws = (char*)d_ws;
  size_t off = 0;
  auto alloc = [&](size_t bytes) -> void* {
    void* p = ws + off;
    off = (off + bytes + 255) & ~(size_t)255;
    return p;
  };
  int*   row_off  = (int*)  alloc((size_t)(n + 1) * sizeof(int));
  int*   bktTotal = (int*)  alloc(512 * sizeof(int));
  int*   bktBase  = (int*)  alloc(513 * sizeof(int));
  int*   bktCur   = (int*)  alloc(512 * sizeof(int));
  int*   dbins    = (int*)  alloc(256 * sizeof(int));
  int*   dcur     = (int*)  alloc(256 * sizeof(int));
  int*   order    = (int*)  alloc((size_t)n * sizeof(int));
  int*   csr_src  = (int*)  alloc((size_t)(nE + n) * sizeof(int));
  int2*  ebuf     = (int2*) alloc((size_t)nE * sizeof(int2));
  unsigned short* xlb16 = (unsigned short*)alloc((size_t)n * 128 * sizeof(unsigned short));
  unsigned short* xrb16 = (unsigned short*)alloc((size_t)n * 128 * sizeof(unsigned short));
  unsigned short* Wt16  = (unsigned short*)alloc(6 * 16384 * sizeof(unsigned short));
  unsigned short* hC16  = (unsigned short*)alloc((size_t)n * 128 * sizeof(unsigned short));
  (void)ws_size; (void)n_in;

  // ---- W prep ----
  prep_w_kernel<<<48, 256, 0, stream>>>(Wl[0], Wr[0], Wl[1], Wr[1], Wl[2], Wr[2], Wt16);

  // ---- bucketed CSR build ----
  hipMemsetAsync(bktTotal, 0, 512 * sizeof(int), stream);
  hipMemsetAsync(dbins, 0, 256 * sizeof(int), stream);
  const int eblocks = (nE + 2048 - 1) / 2048;
  p1_bucket_count<<<eblocks, 256, 0, stream>>>(edst, bktTotal, nE, K);
  p2_scan<<<1, 512, 0, stream>>>(bktTotal, bktBase, bktCur, row_off, K, n, nE);
  p3_partition<<<eblocks, 256, 0, stream>>>(esrc, edst, bktCur, ebuf, nE, K);
  p4_build<<<K, 256, 0, stream>>>(ebuf, bktBase, row_off, csr_src, n);

  // ---- degree sort ----
  const int nblocks = (n + 255) / 256;
  deg_hist<<<nblocks, 256, 0, stream>>>(row_off, dbins, n);
  deg_scan<<<1, 256, 0, stream>>>(dbins, dcur);
  deg_scatter<<<nblocks, 256, 0, stream>>>(row_off, dcur, order, n);

  const int gemm_tiles = (n + 127) / 128;
  const int attn_blocks = (int)(((size_t)n * 16 + 255) / 256);

  // layer 1
  gemm_mfma_kernel<false><<<dim3(gemm_tiles, 2), 256, 0, stream>>>(x, Wt16 + 0 * 32768,
                                                            bl[0], br[0], xlb16, xrb16, n);
  edge_attn_kernel<<<attn_blocks, 256, 0, stream>>>(xlb16, xrb16, row_off, csr_src, order,
                                                    att[0], bias[0], hC16, n, 1);
  // layer 2
  gemm_mfma_kernel<true><<<dim3(gemm_tiles, 2), 256, 0, stream>>>(hC16, Wt16 + 1 * 32768,
                                                            bl[1], br[1], xlb16, xrb16, n);
  edge_attn_kernel<<<attn_blocks, 256, 0, stream>>>(xlb16, xrb16, row_off, csr_src, order,
                                                    att[1], bias[1], hC16, n, 1);
  // layer 3
  gemm_mfma_kernel<true><<<dim3(gemm_tiles, 2), 256, 0, stream>>>(hC16, Wt16 + 2 * 32768,
                                                            bl[2], br[2], xlb16, xrb16, n);
  edge_attn_kernel<<<attn_blocks, 256, 0, stream>>>(xlb16, xrb16, row_off, csr_src, order,
                                                    att[2], bias[2], hC16, n, 0);

  pool_mlp_kernel<<<n_graphs, 128, 0, stream>>>(hC16, batch, n, W4, b4, W5, b5, W6, b6,
                                                (float*)d_out);
}